// Round 9
// baseline (661.621 us; speedup 1.0000x reference)
//
#include <hip/hip_runtime.h>
#include <hip/hip_bf16.h>
#include <math.h>

#define TP_D   896
#define TP_H   8
#define TP_HD  112
#define TP_LQ  1568
#define TP_LK  6272
#define TP_D4  3584
#define TP_F   32
#define TP_P   196

typedef unsigned short u16;
typedef float f32x4 __attribute__((ext_vector_type(4)));
typedef __bf16 bf16x8 __attribute__((ext_vector_type(8)));

__device__ inline float bf2f(u16 u) {
    return __uint_as_float(((unsigned int)u) << 16);
}
__device__ inline u16 f2bf(float f) {
    unsigned int x = __float_as_uint(f);
    unsigned int lsb = (x >> 16) & 1u;
    x += 0x7fffu + lsb;
    return (u16)(x >> 16);
}
__device__ inline ushort4 pack4(float a, float b, float c, float d) {
    return make_ushort4(f2bf(a), f2bf(b), f2bf(c), f2bf(d));
}
// XOR-swizzled 128-col LDS tile index (16B-block swizzle)
__device__ inline int pidx(int row, int col) {
    return row * 128 + (col ^ ((row & 7) << 3));
}

// ---------------------------------------------------------------- casts
// two arrays in one dispatch: [src0, n0) then [src1, n1)
__global__ void cast2_f32_bf16(const float* __restrict__ src0, u16* __restrict__ dst0, int n0,
                               const float* __restrict__ src1, u16* __restrict__ dst1, int n1) {
    int i = (blockIdx.x * blockDim.x + threadIdx.x) * 4;
    const float* s; u16* d; int n;
    if (i < n0) { s = src0; d = dst0; n = n0; }
    else        { i -= n0; s = src1; d = dst1; n = n1; if (i >= n) return; }
    float4 v = *(const float4*)(s + i);
    *(ushort4*)(d + i) = pack4(v.x, v.y, v.z, v.w);
}

// ctx fp32 (atomic-accumulated e*V) -> /l -> bf16
__global__ void cast_div_bf16(const float* __restrict__ src, const float* __restrict__ l,
                              u16* __restrict__ dst) {
    int i = (blockIdx.x * 256 + threadIdx.x) * 4;
    if (i >= TP_LQ * TP_D) return;
    int q = i / TP_D;
    int col = i - q * TP_D;
    int h = col / TP_HD;
    float inv = 1.f / l[h * TP_LQ + q];
    float4 v = *(const float4*)(src + i);
    *(ushort4*)(dst + i) = pack4(v.x * inv, v.y * inv, v.z * inv, v.w * inv);
}

// src fp32 [R][C] -> dst bf16 [C][R].  R,C multiples of 32. block (32,8)
__global__ void transpose_cast(const float* __restrict__ src, u16* __restrict__ dst, int R, int C) {
    __shared__ float t[32][33];
    int bx = blockIdx.x * 32;
    int by = blockIdx.y * 32;
    int tx = threadIdx.x, ty = threadIdx.y;
#pragma unroll
    for (int j = 0; j < 4; ++j)
        t[ty + j * 8][tx] = src[(size_t)(by + ty + j * 8) * C + bx + tx];
    __syncthreads();
#pragma unroll
    for (int j = 0; j < 4; ++j)
        dst[(size_t)(bx + ty + j * 8) * R + by + tx] = f2bf(t[tx][ty + j * 8]);
}

// ---------------------------------------------------------------- GEMM
// C[M,N] = A[M,K] @ Bt[N,K]^T, tile 128m x (NT*32)n, BK=32.
// MODE 4: out bf16 = acc + bias[col] (relu optional)
// MODE 6: split-K: z = k-slice (chunk p.kc); atomicAdd fp32 into outF
// MODE 7: V-proj writing V^T: out bf16 at outB[col*ldc + row]
struct GemmParams {
    const u16* A;  int lda;
    const u16* Bt; int ldb;
    int M, N, K;
    const float* bias;
    float* outF;
    u16* outB; int ldc;
    int relu;
    int kc;
};

#define LDS_STRIDE 56   // bf16 elems

template <int MODE, int NT>
__global__ __launch_bounds__(256, 4) void gemm_bf16(GemmParams p) {
    __shared__ u16 lsA[128 * LDS_STRIDE];
    __shared__ u16 lsB[NT * 32 * LDS_STRIDE];

    const int tid = threadIdx.x;
    const int z = blockIdx.z;
    const u16* A  = p.A;
    const u16* Bt = p.Bt;
    if (MODE == 6) {
        A  += (size_t)z * p.kc;
        Bt += (size_t)z * p.kc;
    }
    const int m0 = blockIdx.y * 128;
    const int n0 = blockIdx.x * (NT * 32);

    const int lane = tid & 63;
    const int w = tid >> 6;
    const int wm = (w >> 1) * 64, wn = (w & 1) * (16 * NT);
    const int c = lane & 15, q = lane >> 4;

    f32x4 acc[4][NT];
#pragma unroll
    for (int i = 0; i < 4; ++i)
#pragma unroll
        for (int j = 0; j < NT; ++j) acc[i][j] = 0.f;

    const int r0 = tid >> 2;
    const int c8 = (tid & 3) * 8;
    int arow0 = m0 + r0;      if (arow0 >= p.M) arow0 = p.M - 1;
    int arow1 = m0 + r0 + 64; if (arow1 >= p.M) arow1 = p.M - 1;
    int brow0 = n0 + r0;      if (brow0 >= p.N) brow0 = p.N - 1;
    int brow1 = n0 + r0 + 64; if (brow1 >= p.N) brow1 = p.N - 1;
    const u16* a0 = A  + (size_t)arow0 * p.lda + c8;
    const u16* a1 = A  + (size_t)arow1 * p.lda + c8;
    const u16* b0 = Bt + (size_t)brow0 * p.ldb + c8;
    const u16* b1 = Bt + (size_t)brow1 * p.ldb + c8;

    const int KT = (p.K + 31) >> 5;
    for (int kt = 0; kt < KT; ++kt) {
        const int k0 = kt << 5;
        const bool valid = (k0 + c8 + 8) <= p.K;
        uint4 zv = make_uint4(0, 0, 0, 0);
        uint4 va0 = valid ? *(const uint4*)(a0 + k0) : zv;
        uint4 va1 = valid ? *(const uint4*)(a1 + k0) : zv;
        uint4 vb0 = valid ? *(const uint4*)(b0 + k0) : zv;
        uint4 vb1 = (NT == 4 && valid) ? *(const uint4*)(b1 + k0) : zv;
        *(uint4*)(&lsA[r0 * LDS_STRIDE + c8])        = va0;
        *(uint4*)(&lsA[(r0 + 64) * LDS_STRIDE + c8]) = va1;
        *(uint4*)(&lsB[r0 * LDS_STRIDE + c8])        = vb0;
        if (NT == 4)
            *(uint4*)(&lsB[(r0 + 64) * LDS_STRIDE + c8]) = vb1;
        __syncthreads();

        bf16x8 af[4], bfv[NT];
#pragma unroll
        for (int mi = 0; mi < 4; ++mi)
            af[mi] = *(const bf16x8*)(&lsA[(wm + mi * 16 + c) * LDS_STRIDE + q * 8]);
#pragma unroll
        for (int ni = 0; ni < NT; ++ni)
            bfv[ni] = *(const bf16x8*)(&lsB[(wn + ni * 16 + c) * LDS_STRIDE + q * 8]);
#pragma unroll
        for (int mi = 0; mi < 4; ++mi)
#pragma unroll
            for (int ni = 0; ni < NT; ++ni)
                acc[mi][ni] = __builtin_amdgcn_mfma_f32_16x16x32_bf16(af[mi], bfv[ni], acc[mi][ni], 0, 0, 0);
        __syncthreads();
    }

    if (MODE == 7) {
#pragma unroll
        for (int ni = 0; ni < NT; ++ni) {
            const int col = n0 + wn + ni * 16 + c;
            const float bv = p.bias[col];
#pragma unroll
            for (int mi = 0; mi < 4; ++mi) {
                const int mbase = m0 + wm + mi * 16 + q * 4;
                f32x4 a = acc[mi][ni];
                *(ushort4*)(p.outB + (size_t)col * p.ldc + mbase) =
                    pack4(a[0] + bv, a[1] + bv, a[2] + bv, a[3] + bv);
            }
        }
        return;
    }

#pragma unroll
    for (int mi = 0; mi < 4; ++mi) {
#pragma unroll
        for (int r = 0; r < 4; ++r) {
            const int row = m0 + wm + mi * 16 + q * 4 + r;
            if (row >= p.M) continue;
#pragma unroll
            for (int ni = 0; ni < NT; ++ni) {
                const int col = n0 + wn + ni * 16 + c;
                float v = acc[mi][ni][r];
                if (MODE == 4) {
                    v += p.bias[col];
                    if (p.relu) v = v > 0.f ? v : 0.f;
                    p.outB[(size_t)row * p.ldc + col] = f2bf(v);
                } else if (MODE == 6) {
                    atomicAdd(&p.outF[(size_t)row * p.ldc + col], v);
                }
            }
        }
    }
}

// ---------------------------------------------------------------- fused attention
// R4 layouts, re-choreographed: Q fragments in registers; single 32 KB lsKV
// buffer staged whole (K-tile then V-tile) -> 4 barriers per key-block.
// grid (7 k-chunks, 13 q-tiles of 128, 8 heads).
__global__ __launch_bounds__(256, 2) void attn_fused(
        const u16* __restrict__ Qf, const u16* __restrict__ Kf,
        const u16* __restrict__ Vtf, u16* __restrict__ E,
        float* __restrict__ lsum, float* __restrict__ ctxF, float scale) {
    __shared__ u16 lsKV[128 * 128];  // K tile (rows=keys,cols=d) then V tile (rows=d,cols=keys)
    __shared__ u16 lsP[128 * 128];   // e tile, swizzled

    const int ks  = blockIdx.x;
    const int m0  = blockIdx.y * 128;
    const int h   = blockIdx.z;
    const int tid = threadIdx.x;
    const int lane = tid & 63, w = tid >> 6;
    const int wm = (w >> 1) * 64, wn = (w & 1) * 64;
    const int c = lane & 15, q = lane >> 4;

    // ---- Q fragments in registers: qf[mi][kt] = Q[m0+wm+mi*16+c][kt*32+q*8 ..+8]
    bf16x8 qf[4][4];
#pragma unroll
    for (int mi = 0; mi < 4; ++mi) {
        int qr = m0 + wm + mi * 16 + c; if (qr > TP_LQ - 1) qr = TP_LQ - 1;
        const u16* src = Qf + (size_t)qr * TP_D + h * TP_HD;
#pragma unroll
        for (int kt = 0; kt < 4; ++kt) {
            int d0 = kt * 32 + q * 8;
            if (d0 + 8 <= TP_HD) qf[mi][kt] = *(const bf16x8*)(src + d0);
            else { union { int4 i; bf16x8 v; } u; u.i = make_int4(0, 0, 0, 0); qf[mi][kt] = u.v; }
        }
    }

    const int srow = tid >> 1;           // 0..127
    const int shalf = (tid & 1) * 64;
    const int keybase = ks * 896;

    f32x4 acc_pv[4][4];
#pragma unroll
    for (int i = 0; i < 4; ++i)
#pragma unroll
        for (int j = 0; j < 4; ++j) acc_pv[i][j] = 0.f;
    float rs[4] = {0.f, 0.f, 0.f, 0.f};

    for (int kb = 0; kb < 7; ++kb) {
        const int kblk = keybase + kb * 128;

        // ---- stage K tile whole (rows=keys 0..127, cols=d zero-padded to 128)
        {
            const u16* src = Kf + (size_t)(kblk + srow) * TP_D + h * TP_HD;
#pragma unroll
            for (int j = 0; j < 8; ++j) {
                int col = shalf + j * 8;
                uint4 v = make_uint4(0, 0, 0, 0);
                if (col + 8 <= TP_HD) v = *(const uint4*)(src + col);
                *(uint4*)(&lsKV[pidx(srow, col)]) = v;
            }
        }
        __syncthreads();   // b1: K staged (also: all waves past prior PV)

        // ---- S phase: 16 MFMAs, no barriers (A=K from lsKV, B=Q regs)
        f32x4 acc_s[4][4];
#pragma unroll
        for (int i = 0; i < 4; ++i)
#pragma unroll
            for (int j = 0; j < 4; ++j) acc_s[i][j] = 0.f;
#pragma unroll
        for (int kt = 0; kt < 4; ++kt) {
            bf16x8 kf[4];
#pragma unroll
            for (int ni = 0; ni < 4; ++ni)
                kf[ni] = *(const bf16x8*)(&lsKV[pidx(wn + ni * 16 + c, kt * 32 + q * 8)]);
#pragma unroll
            for (int mi = 0; mi < 4; ++mi)
#pragma unroll
                for (int ni = 0; ni < 4; ++ni)
                    acc_s[mi][ni] = __builtin_amdgcn_mfma_f32_16x16x32_bf16(kf[ni], qf[mi][kt], acc_s[mi][ni], 0, 0, 0);
        }

        // ---- epilogue: e = exp(s*scale) -> E (bf16) + lsP + reg row-sums
        // D layout: key = wn+ni*16+q*4+r, query = wm+mi*16+c
#pragma unroll
        for (int mi = 0; mi < 4; ++mi) {
            const int prow = wm + mi * 16 + c;
            const int qr = m0 + prow;
            const bool qv = qr < TP_LQ;
            float rp = 0.f;
#pragma unroll
            for (int ni = 0; ni < 4; ++ni) {
                f32x4 a = acc_s[mi][ni];
                float e0 = __expf(fminf(a[0] * scale, 30.f));
                float e1 = __expf(fminf(a[1] * scale, 30.f));
                float e2 = __expf(fminf(a[2] * scale, 30.f));
                float e3 = __expf(fminf(a[3] * scale, 30.f));
                rp += (e0 + e1) + (e2 + e3);
                ushort4 pk = pack4(e0, e1, e2, e3);
                const int kcol = wn + ni * 16 + q * 4;
                if (qv)
                    *(ushort4*)(E + ((size_t)h * TP_LQ + qr) * TP_LK + kblk + kcol) = pk;
                *(ushort4*)(&lsP[pidx(prow, kcol)]) = pk;
            }
            rs[mi] += rp;
        }
        __syncthreads();   // b2: lsP visible; S reads of lsKV done

        // ---- stage V tile whole (rows=d 0..111 pad 128, cols=keys)
        {
            uint4 zv = make_uint4(0, 0, 0, 0);
            const u16* src = Vtf + ((size_t)h * TP_HD + srow) * TP_LK + kblk;
#pragma unroll
            for (int j = 0; j < 8; ++j) {
                int col = shalf + j * 8;
                uint4 v = (srow < TP_HD) ? *(const uint4*)(src + col) : zv;
                *(uint4*)(&lsKV[pidx(srow, col)]) = v;
            }
        }
        __syncthreads();   // b3: V staged

        // ---- PV phase: 16 MFMAs, no barriers (A=P from lsP, B=V from lsKV)
#pragma unroll
        for (int kt = 0; kt < 4; ++kt) {
            bf16x8 ap[4], bv[4];
#pragma unroll
            for (int mi = 0; mi < 4; ++mi)
                ap[mi] = *(const bf16x8*)(&lsP[pidx(wm + mi * 16 + c, kt * 32 + q * 8)]);
#pragma unroll
            for (int ni = 0; ni < 4; ++ni)
                bv[ni] = *(const bf16x8*)(&lsKV[pidx(wn + ni * 16 + c, kt * 32 + q * 8)]);
#pragma unroll
            for (int mi = 0; mi < 4; ++mi)
#pragma unroll
                for (int ni = 0; ni < 4; ++ni)
                    acc_pv[mi][ni] = __builtin_amdgcn_mfma_f32_16x16x32_bf16(ap[mi], bv[ni], acc_pv[mi][ni], 0, 0, 0);
        }
        __syncthreads();   // b4: PV reads of lsKV/lsP done
    }

    // ---- row-sum atomics (l)
#pragma unroll
    for (int mi = 0; mi < 4; ++mi) {
        float rp = rs[mi];
        rp += __shfl_xor(rp, 16, 64);
        rp += __shfl_xor(rp, 32, 64);
        const int qr = m0 + wm + mi * 16 + c;
        if (q == 0 && qr < TP_LQ) atomicAdd(&lsum[h * TP_LQ + qr], rp);
    }
    // ---- ctx atomics: D[m=query wm+mi*16+q*4+r][n=d wn+ni*16+c]
#pragma unroll
    for (int mi = 0; mi < 4; ++mi) {
#pragma unroll
        for (int r = 0; r < 4; ++r) {
            const int qr = m0 + wm + mi * 16 + q * 4 + r;
            if (qr >= TP_LQ) continue;
#pragma unroll
            for (int ni = 0; ni < 4; ++ni) {
                const int d = wn + ni * 16 + c;
                if (d < TP_HD)
                    atomicAdd(&ctxF[(size_t)qr * TP_D + h * TP_HD + d], acc_pv[mi][ni][r]);
            }
        }
    }
}

// colsum[k] += sum over rows of e[row][k]/l[row]; vec4 columns per thread
__global__ void colsum_kernel(const u16* __restrict__ E, const float* __restrict__ l,
                              float* __restrict__ colsum, int nrows) {
    int c4 = blockIdx.x * 256 + threadIdx.x;   // vec4 col index
    if (c4 >= TP_LK / 4) return;
    int chunk = (nrows + gridDim.y - 1) / gridDim.y;
    int r0 = blockIdx.y * chunk;
    int r1 = r0 + chunk; if (r1 > nrows) r1 = nrows;
    float a0 = 0.f, a1 = 0.f, a2 = 0.f, a3 = 0.f;
    for (int r = r0; r < r1; ++r) {
        float inv = 1.f / l[r];
        ushort4 u = ((const ushort4*)(E + (size_t)r * TP_LK))[c4];
        a0 += bf2f(u.x) * inv; a1 += bf2f(u.y) * inv;
        a2 += bf2f(u.z) * inv; a3 += bf2f(u.w) * inv;
    }
    atomicAdd(&colsum[4 * c4 + 0], a0);
    atomicAdd(&colsum[4 * c4 + 1], a1);
    atomicAdd(&colsum[4 * c4 + 2], a2);
    atomicAdd(&colsum[4 * c4 + 3], a3);
}

// ---------------------------------------------------------------- layernorm
// t = x + bias + res; out = LN(t)*g + b
__global__ __launch_bounds__(256) void layernorm_rows(const float* __restrict__ x,
        const float* __restrict__ bias, const float* __restrict__ res,
        const float* __restrict__ g, const float* __restrict__ b,
        float* __restrict__ outF, u16* __restrict__ outB) {
    const int tid = threadIdx.x;
    const float* xr = x + (size_t)blockIdx.x * TP_D;
    const float* rr = res + (size_t)blockIdx.x * TP_D;
    float v[4];
#pragma unroll
    for (int i = 0; i < 4; ++i) {
        int idx = tid + i * 256;
        v[i] = (idx < TP_D) ? (xr[idx] + bias[idx] + rr[idx]) : 0.f;
    }
    float s = v[0] + v[1] + v[2] + v[3];
    __shared__ float red[4];
#pragma unroll
    for (int o = 32; o > 0; o >>= 1) s += __shfl_xor(s, o, 64);
    if ((tid & 63) == 0) red[tid >> 6] = s;
    __syncthreads();
    const float mu = (red[0] + red[1] + red[2] + red[3]) * (1.f / TP_D);
    __syncthreads();
    float ss = 0.f;
#pragma unroll
    for (int i = 0; i < 4; ++i) {
        int idx = tid + i * 256;
        if (idx < TP_D) { float d = v[i] - mu; ss += d * d; }
    }
#pragma unroll
    for (int o = 32; o > 0; o >>= 1) ss += __shfl_xor(ss, o, 64);
    if ((tid & 63) == 0) red[tid >> 6] = ss;
    __syncthreads();
    const float var = (red[0] + red[1] + red[2] + red[3]) * (1.f / TP_D);
    const float rsq = rsqrtf(var + 1e-12f);
    float* of = outF + (size_t)blockIdx.x * TP_D;
    u16* obp = outB ? outB + (size_t)blockIdx.x * TP_D : nullptr;
#pragma unroll
    for (int i = 0; i < 4; ++i) {
        int idx = tid + i * 256;
        if (idx < TP_D) {
            float y = (v[i] - mu) * rsq * g[idx] + b[idx];
            of[idx] = y;
            if (obp) obp[idx] = f2bf(y);
        }
    }
}

__global__ void frame_scores_kernel(const float* __restrict__ colsum, float* __restrict__ out) {
    const int tid = threadIdx.x;
    float v = (tid < TP_P) ? colsum[blockIdx.x * TP_P + tid] : 0.f;
    __shared__ float red[4];
#pragma unroll
    for (int o = 32; o > 0; o >>= 1) v += __shfl_xor(v, o, 64);
    if ((tid & 63) == 0) red[tid >> 6] = v;
    __syncthreads();
    if (tid == 0) out[blockIdx.x] = (red[0] + red[1] + red[2] + red[3]) * (1.f / TP_P);
}

// ---------------------------------------------------------------- launch
extern "C" void kernel_launch(void* const* d_in, const int* in_sizes, int n_in,
                              void* d_out, int out_size, void* d_ws, size_t ws_size,
                              hipStream_t stream) {
    const float* img  = (const float*)d_in[0];
    const float* mem  = (const float*)d_in[1];
    const float* qW   = (const float*)d_in[2];
    const float* qb   = (const float*)d_in[3];
    const float* kW   = (const float*)d_in[4];
    const float* kb   = (const float*)d_in[5];
    const float* vW   = (const float*)d_in[6];
    const float* vb   = (const float*)d_in[7];
    const float* oW   = (const float*)d_in[8];
    const float* ob   = (const float*)d_in[9];
    const float* ln1g = (const float*)d_in[10];
    const float* ln1b = (const float*)d_in[11];
    const float* mW   = (const float*)d_in[12];
    const float* mb   = (const float*)d_in[13];
    const float* pW   = (const float*)d_in[14];
    const float* pb   = (const float*)d_in[15];
    const float* ln2g = (const float*)d_in[16];
    const float* ln2b = (const float*)d_in[17];
    float* out = (float*)d_out;

    char* base = (char*)d_ws;
    size_t off = 0;
    auto take = [&](size_t nbytes) -> void* {
        void* p = base + off;
        off += (nbytes + 255) & ~(size_t)255;
        return p;
    };

    u16* imgB  = (u16*)take((size_t)TP_LK * TP_D * 2);
    u16* memB  = (u16*)take((size_t)TP_LQ * TP_D * 2);
    u16* qWt   = (u16*)take((size_t)TP_D * TP_D * 2);
    u16* kWt   = (u16*)take((size_t)TP_D * TP_D * 2);
    u16* vWt   = (u16*)take((size_t)TP_D * TP_D * 2);
    u16* oWt   = (u16*)take((size_t)TP_D * TP_D * 2);
    u16* mWt   = (u16*)take((size_t)TP_D * TP_D4 * 2);
    u16* pWt   = (u16*)take((size_t)TP_D * TP_D4 * 2);
    u16* Qf    = (u16*)take((size_t)TP_LQ * TP_D * 2);
    u16* Kf    = (u16*)take((size_t)TP_LK * TP_D * 2);
    u16* Vtf   = (u16*)take((size_t)TP_LK * TP_D * 2);
    u16* ctxB  = (u16*)take((size_t)TP_LQ * TP_D * 2);
    float* attn  = (float*)take((size_t)TP_LQ * TP_D * 4);
    u16* attnB = (u16*)take((size_t)TP_LQ * TP_D * 2);
    u16* hidden= (u16*)take((size_t)TP_LQ * TP_D4 * 2);
    u16* E     = (u16*)take((size_t)TP_H * TP_LQ * TP_LK * 2);
    // ---- contiguous zero region (single memset) ----
    float* ctxF  = (float*)take((size_t)TP_LQ * TP_D * 4);
    float* pre1  = (float*)take((size_t)TP_LQ * TP_D * 4);
    float* pre2  = (float*)take((size_t)TP_LQ * TP_D * 4);
    float* colsum= (float*)take((size_t)TP_LK * 4);
    float* lsum  = (float*)take((size_t)TP_H * TP_LQ * 4);
    size_t zlen = (char*)(lsum + TP_H * TP_LQ) - (char*)ctxF;

    // ---- casts / transposes / zero-init
    {
        int n0 = TP_LK * TP_D, n1 = TP_LQ * TP_D;
        cast2_f32_bf16<<<((n0 + n1) / 4 + 255) / 256, 256, 0, stream>>>(img, imgB, n0, mem, memB, n1);
    }
    transpose_cast<<<dim3(28, 28), dim3(32, 8), 0, stream>>>(qW, qWt, TP_D, TP_D);
    transpose_cast<<<dim3(28, 28), dim3(32, 8), 0, stream>>>(kW, kWt, TP_D, TP_D);
    transpose_cast<<<dim3(28, 28), dim3(32, 8), 0, stream>>>(vW, vWt, TP_D, TP_D);
    transpose_cast<<<dim3(28, 28), dim3(32, 8), 0, stream>>>(oW, oWt, TP_D, TP_D);
    transpose_cast<<<dim3(TP_D4 / 32, TP_D / 32), dim3(32, 8), 0, stream>>>(mW, mWt, TP_D, TP_D4);
    transpose_cast<<<dim3(TP_D / 32, TP_D4 / 32), dim3(32, 8), 0, stream>>>(pW, pWt, TP_D4, TP_D);
    hipMemsetAsync(ctxF, 0, zlen, stream);

    // ---- QKV projections (NT=2 tiles for occupancy)
    {
        GemmParams p{};
        p.A = memB; p.lda = TP_D;
        p.Bt = qWt; p.ldb = TP_D;
        p.M = TP_LQ; p.N = TP_D; p.K = TP_D;
        p.bias = qb; p.outB = Qf; p.ldc = TP_D; p.relu = 0;
        gemm_bf16<4, 2><<<dim3(14, 13, 1), 256, 0, stream>>>(p);
    }
    {
        GemmParams p{};
        p.A = imgB; p.lda = TP_D;
        p.Bt = kWt; p.ldb = TP_D;
        p.M = TP_LK; p.N = TP_D; p.K = TP_D;
        p.bias = kb; p.outB = Kf; p.ldc = TP_D; p.relu = 0;
        gemm_bf16<4, 2><<<dim3(14, 49, 1), 256, 0, stream>>>(p);
    }
    {   // V-projection writing V^T [896][6272] directly
        GemmParams p{};
        p.A = imgB; p.lda = TP_D;
        p.Bt = vWt; p.ldb = TP_D;
        p.M = TP_LK; p.N = TP_D; p.K = TP_D;
        p.bias = vb; p.outB = Vtf; p.ldc = TP_LK;
        gemm_bf16<7, 2><<<dim3(14, 49, 1), 256, 0, stream>>>(p);
    }

    // ---- fused attention (S + exp + E + l + PV), colsum over E, normalize
    const float scale = 0.09449111825230679f;  // 1/sqrt(112)
    attn_fused<<<dim3(7, 13, TP_H), 256, 0, stream>>>(Qf, Kf, Vtf, E, lsum, ctxF, scale);
    colsum_kernel<<<dim3(7, 448), 256, 0, stream>>>(E, lsum, colsum, TP_H * TP_LQ);
    cast_div_bf16<<<(TP_LQ * TP_D / 4 + 255) / 256, 256, 0, stream>>>(ctxF, lsum, ctxB);

    // ---- O-projection split-K x2 -> pre1 (bias+residual in LN1)
    {
        GemmParams p{};
        p.A = ctxB; p.lda = TP_D;
        p.Bt = oWt; p.ldb = TP_D;
        p.M = TP_LQ; p.N = TP_D; p.K = 448; p.kc = 448;
        p.outF = pre1; p.ldc = TP_D;
        gemm_bf16<6, 2><<<dim3(14, 13, 2), 256, 0, stream>>>(p);
    }
    layernorm_rows<<<TP_LQ, 256, 0, stream>>>(pre1, ob, mem, ln1g, ln1b, attn, attnB);

    // ---- MLP
    {
        GemmParams p{};
        p.A = attnB; p.lda = TP_D;
        p.Bt = mWt; p.ldb = TP_D;
        p.M = TP_LQ; p.N = TP_D4; p.K = TP_D;
        p.bias = mb; p.outB = hidden; p.ldc = TP_D4; p.relu = 1;
        gemm_bf16<4, 2><<<dim3(56, 13, 1), 256, 0, stream>>>(p);
    }
    {   // MLP2 split-K x4 -> pre2 (bias+residual in LN2)
        GemmParams p{};
        p.A = hidden; p.lda = TP_D4;
        p.Bt = pWt; p.ldb = TP_D4;
        p.M = TP_LQ; p.N = TP_D; p.K = 896; p.kc = 896;
        p.outF = pre2; p.ldc = TP_D;
        gemm_bf16<6, 2><<<dim3(14, 13, 4), 256, 0, stream>>>(p);
    }
    layernorm_rows<<<TP_LQ, 256, 0, stream>>>(pre2, pb, attn, ln2g, ln2b, out, nullptr);

    // ---- frame scores
    frame_scores_kernel<<<TP_F, 256, 0, stream>>>(colsum, out + (size_t)TP_LQ * TP_D);
}

// Round 10
// 517.869 us; speedup vs baseline: 1.2776x; 1.2776x over previous
//
#include <hip/hip_runtime.h>
#include <hip/hip_bf16.h>
#include <math.h>

#define TP_D   896
#define TP_H   8
#define TP_HD  112
#define TP_LQ  1568
#define TP_LK  6272
#define TP_D4  3584
#define TP_F   32
#define TP_P   196

typedef unsigned short u16;
typedef float f32x4 __attribute__((ext_vector_type(4)));
typedef __bf16 bf16x8 __attribute__((ext_vector_type(8)));

__device__ inline float bf2f(u16 u) {
    return __uint_as_float(((unsigned int)u) << 16);
}
__device__ inline u16 f2bf(float f) {
    unsigned int x = __float_as_uint(f);
    unsigned int lsb = (x >> 16) & 1u;
    x += 0x7fffu + lsb;
    return (u16)(x >> 16);
}
__device__ inline ushort4 pack4(float a, float b, float c, float d) {
    return make_ushort4(f2bf(a), f2bf(b), f2bf(c), f2bf(d));
}
// XOR-swizzled 128-col LDS tile index (16B-block swizzle)
__device__ inline int pidx(int row, int col) {
    return row * 128 + (col ^ ((row & 7) << 3));
}

// ---------------------------------------------------------------- casts
// two arrays in one dispatch: [src0, n0) then [src1, n1)
__global__ void cast2_f32_bf16(const float* __restrict__ src0, u16* __restrict__ dst0, int n0,
                               const float* __restrict__ src1, u16* __restrict__ dst1, int n1) {
    int i = (blockIdx.x * blockDim.x + threadIdx.x) * 4;
    const float* s; u16* d; int n;
    if (i < n0) { s = src0; d = dst0; n = n0; }
    else        { i -= n0; s = src1; d = dst1; n = n1; if (i >= n) return; }
    float4 v = *(const float4*)(s + i);
    *(ushort4*)(d + i) = pack4(v.x, v.y, v.z, v.w);
}

// ctx fp32 (atomic-accumulated e*V) -> /l -> bf16
__global__ void cast_div_bf16(const float* __restrict__ src, const float* __restrict__ l,
                              u16* __restrict__ dst) {
    int i = (blockIdx.x * 256 + threadIdx.x) * 4;
    if (i >= TP_LQ * TP_D) return;
    int q = i / TP_D;
    int col = i - q * TP_D;
    int h = col / TP_HD;
    float inv = 1.f / l[h * TP_LQ + q];
    float4 v = *(const float4*)(src + i);
    *(ushort4*)(dst + i) = pack4(v.x * inv, v.y * inv, v.z * inv, v.w * inv);
}

// src fp32 [R][C] -> dst bf16 [C][R].  R,C multiples of 32. block (32,8)
__global__ void transpose_cast(const float* __restrict__ src, u16* __restrict__ dst, int R, int C) {
    __shared__ float t[32][33];
    int bx = blockIdx.x * 32;
    int by = blockIdx.y * 32;
    int tx = threadIdx.x, ty = threadIdx.y;
#pragma unroll
    for (int j = 0; j < 4; ++j)
        t[ty + j * 8][tx] = src[(size_t)(by + ty + j * 8) * C + bx + tx];
    __syncthreads();
#pragma unroll
    for (int j = 0; j < 4; ++j)
        dst[(size_t)(bx + ty + j * 8) * R + by + tx] = f2bf(t[tx][ty + j * 8]);
}

// four 896x896 transposes in one dispatch (z selects)
__global__ void transpose_cast4(const float* __restrict__ s0, u16* __restrict__ d0,
                                const float* __restrict__ s1, u16* __restrict__ d1,
                                const float* __restrict__ s2, u16* __restrict__ d2,
                                const float* __restrict__ s3, u16* __restrict__ d3) {
    __shared__ float t[32][33];
    const float* src; u16* dst;
    switch (blockIdx.z) {
        case 0: src = s0; dst = d0; break;
        case 1: src = s1; dst = d1; break;
        case 2: src = s2; dst = d2; break;
        default: src = s3; dst = d3; break;
    }
    int bx = blockIdx.x * 32;
    int by = blockIdx.y * 32;
    int tx = threadIdx.x, ty = threadIdx.y;
#pragma unroll
    for (int j = 0; j < 4; ++j)
        t[ty + j * 8][tx] = src[(size_t)(by + ty + j * 8) * TP_D + bx + tx];
    __syncthreads();
#pragma unroll
    for (int j = 0; j < 4; ++j)
        dst[(size_t)(bx + ty + j * 8) * TP_D + by + tx] = f2bf(t[tx][ty + j * 8]);
}

// ---------------------------------------------------------------- GEMM
// C[M,N] = A[M,K] @ Bt[N,K]^T, tile 128m x (NT*32)n, BK=32.
// MODE 4: out bf16 = acc + bias[col] (relu optional)
// MODE 6: split-K: z = k-slice (chunk p.kc); atomicAdd fp32 into outF
struct GemmParams {
    const u16* A;  int lda;
    const u16* Bt; int ldb;
    int M, N, K;
    const float* bias;
    float* outF;
    u16* outB; int ldc;
    int relu;
    int kc;
};

#define LDS_STRIDE 56   // bf16 elems

template <int MODE, int NT>
__global__ __launch_bounds__(256, 4) void gemm_bf16(GemmParams p) {
    __shared__ u16 lsA[128 * LDS_STRIDE];
    __shared__ u16 lsB[NT * 32 * LDS_STRIDE];

    const int tid = threadIdx.x;
    const int z = blockIdx.z;
    const u16* A  = p.A;
    const u16* Bt = p.Bt;
    if (MODE == 6) {
        A  += (size_t)z * p.kc;
        Bt += (size_t)z * p.kc;
    }
    const int m0 = blockIdx.y * 128;
    const int n0 = blockIdx.x * (NT * 32);

    const int lane = tid & 63;
    const int w = tid >> 6;
    const int wm = (w >> 1) * 64, wn = (w & 1) * (16 * NT);
    const int c = lane & 15, q = lane >> 4;

    f32x4 acc[4][NT];
#pragma unroll
    for (int i = 0; i < 4; ++i)
#pragma unroll
        for (int j = 0; j < NT; ++j) acc[i][j] = 0.f;

    const int r0 = tid >> 2;
    const int c8 = (tid & 3) * 8;
    int arow0 = m0 + r0;      if (arow0 >= p.M) arow0 = p.M - 1;
    int arow1 = m0 + r0 + 64; if (arow1 >= p.M) arow1 = p.M - 1;
    int brow0 = n0 + r0;      if (brow0 >= p.N) brow0 = p.N - 1;
    int brow1 = n0 + r0 + 64; if (brow1 >= p.N) brow1 = p.N - 1;
    const u16* a0 = A  + (size_t)arow0 * p.lda + c8;
    const u16* a1 = A  + (size_t)arow1 * p.lda + c8;
    const u16* b0 = Bt + (size_t)brow0 * p.ldb + c8;
    const u16* b1 = Bt + (size_t)brow1 * p.ldb + c8;

    const int KT = (p.K + 31) >> 5;
    for (int kt = 0; kt < KT; ++kt) {
        const int k0 = kt << 5;
        const bool valid = (k0 + c8 + 8) <= p.K;
        uint4 zv = make_uint4(0, 0, 0, 0);
        uint4 va0 = valid ? *(const uint4*)(a0 + k0) : zv;
        uint4 va1 = valid ? *(const uint4*)(a1 + k0) : zv;
        uint4 vb0 = valid ? *(const uint4*)(b0 + k0) : zv;
        uint4 vb1 = (NT == 4 && valid) ? *(const uint4*)(b1 + k0) : zv;
        *(uint4*)(&lsA[r0 * LDS_STRIDE + c8])        = va0;
        *(uint4*)(&lsA[(r0 + 64) * LDS_STRIDE + c8]) = va1;
        *(uint4*)(&lsB[r0 * LDS_STRIDE + c8])        = vb0;
        if (NT == 4)
            *(uint4*)(&lsB[(r0 + 64) * LDS_STRIDE + c8]) = vb1;
        __syncthreads();

        bf16x8 af[4], bfv[NT];
#pragma unroll
        for (int mi = 0; mi < 4; ++mi)
            af[mi] = *(const bf16x8*)(&lsA[(wm + mi * 16 + c) * LDS_STRIDE + q * 8]);
#pragma unroll
        for (int ni = 0; ni < NT; ++ni)
            bfv[ni] = *(const bf16x8*)(&lsB[(wn + ni * 16 + c) * LDS_STRIDE + q * 8]);
#pragma unroll
        for (int mi = 0; mi < 4; ++mi)
#pragma unroll
            for (int ni = 0; ni < NT; ++ni)
                acc[mi][ni] = __builtin_amdgcn_mfma_f32_16x16x32_bf16(af[mi], bfv[ni], acc[mi][ni], 0, 0, 0);
        __syncthreads();
    }

#pragma unroll
    for (int mi = 0; mi < 4; ++mi) {
#pragma unroll
        for (int r = 0; r < 4; ++r) {
            const int row = m0 + wm + mi * 16 + q * 4 + r;
            if (row >= p.M) continue;
#pragma unroll
            for (int ni = 0; ni < NT; ++ni) {
                const int col = n0 + wn + ni * 16 + c;
                float v = acc[mi][ni][r];
                if (MODE == 4) {
                    v += p.bias[col];
                    if (p.relu) v = v > 0.f ? v : 0.f;
                    p.outB[(size_t)row * p.ldc + col] = f2bf(v);
                } else if (MODE == 6) {
                    atomicAdd(&p.outF[(size_t)row * p.ldc + col], v);
                }
            }
        }
    }
}

// ---------------------------------------------------------------- QKV projection
// One dispatch, z in {0:K-proj, 1:V-proj (writes V^T), 2:Q-proj}.
// NT=2 body (64-wide n tiles), K = 896.
__global__ __launch_bounds__(256, 4) void qkv_proj(
        const u16* __restrict__ imgB, const u16* __restrict__ memB,
        const u16* __restrict__ kWt, const u16* __restrict__ vWt, const u16* __restrict__ qWt,
        const float* __restrict__ kb, const float* __restrict__ vb, const float* __restrict__ qb,
        u16* __restrict__ Kf, u16* __restrict__ Vtf, u16* __restrict__ Qf) {
    __shared__ u16 lsA[128 * LDS_STRIDE];
    __shared__ u16 lsB[64 * LDS_STRIDE];

    const int z = blockIdx.z;
    const u16* A; const u16* Bt; const float* bias; int M;
    if (z == 0)      { A = imgB; Bt = kWt; bias = kb; M = TP_LK; }
    else if (z == 1) { A = imgB; Bt = vWt; bias = vb; M = TP_LK; }
    else             { A = memB; Bt = qWt; bias = qb; M = TP_LQ; }

    const int m0 = blockIdx.y * 128;
    if (m0 >= M) return;
    const int n0 = blockIdx.x * 64;

    const int tid = threadIdx.x;
    const int lane = tid & 63;
    const int w = tid >> 6;
    const int wm = (w >> 1) * 64, wn = (w & 1) * 32;
    const int c = lane & 15, q = lane >> 4;

    f32x4 acc[4][2];
#pragma unroll
    for (int i = 0; i < 4; ++i) { acc[i][0] = 0.f; acc[i][1] = 0.f; }

    const int r0 = tid >> 2;
    const int c8 = (tid & 3) * 8;
    int arow0 = m0 + r0;      if (arow0 >= M) arow0 = M - 1;
    int arow1 = m0 + r0 + 64; if (arow1 >= M) arow1 = M - 1;
    const u16* a0 = A + (size_t)arow0 * TP_D + c8;
    const u16* a1 = A + (size_t)arow1 * TP_D + c8;
    const u16* b0 = Bt + (size_t)(n0 + r0) * TP_D + c8;

    for (int kt = 0; kt < 28; ++kt) {
        const int k0 = kt << 5;
        uint4 va0 = *(const uint4*)(a0 + k0);
        uint4 va1 = *(const uint4*)(a1 + k0);
        uint4 vb0 = *(const uint4*)(b0 + k0);
        *(uint4*)(&lsA[r0 * LDS_STRIDE + c8])        = va0;
        *(uint4*)(&lsA[(r0 + 64) * LDS_STRIDE + c8]) = va1;
        *(uint4*)(&lsB[r0 * LDS_STRIDE + c8])        = vb0;
        __syncthreads();

        bf16x8 af[4], bfv[2];
#pragma unroll
        for (int mi = 0; mi < 4; ++mi)
            af[mi] = *(const bf16x8*)(&lsA[(wm + mi * 16 + c) * LDS_STRIDE + q * 8]);
#pragma unroll
        for (int ni = 0; ni < 2; ++ni)
            bfv[ni] = *(const bf16x8*)(&lsB[(wn + ni * 16 + c) * LDS_STRIDE + q * 8]);
#pragma unroll
        for (int mi = 0; mi < 4; ++mi)
#pragma unroll
            for (int ni = 0; ni < 2; ++ni)
                acc[mi][ni] = __builtin_amdgcn_mfma_f32_16x16x32_bf16(af[mi], bfv[ni], acc[mi][ni], 0, 0, 0);
        __syncthreads();
    }

    if (z == 1) {
        // V^T epilogue: lane regs = 4 consecutive rows, contiguous along V^T inner dim
#pragma unroll
        for (int ni = 0; ni < 2; ++ni) {
            const int col = n0 + wn + ni * 16 + c;
            const float bv = bias[col];
#pragma unroll
            for (int mi = 0; mi < 4; ++mi) {
                const int mbase = m0 + wm + mi * 16 + q * 4;
                f32x4 a = acc[mi][ni];
                *(ushort4*)(Vtf + (size_t)col * TP_LK + mbase) =
                    pack4(a[0] + bv, a[1] + bv, a[2] + bv, a[3] + bv);
            }
        }
        return;
    }

    u16* outB = (z == 0) ? Kf : Qf;
#pragma unroll
    for (int mi = 0; mi < 4; ++mi) {
#pragma unroll
        for (int r = 0; r < 4; ++r) {
            const int row = m0 + wm + mi * 16 + q * 4 + r;
            if (row >= M) continue;
#pragma unroll
            for (int ni = 0; ni < 2; ++ni) {
                const int col = n0 + wn + ni * 16 + c;
                outB[(size_t)row * TP_D + col] = f2bf(acc[mi][ni][r] + bias[col]);
            }
        }
    }
}

// ---------------------------------------------------------------- fused attention
// R8-verbatim (measured 150 us): grid (7 k-chunks, 13 q-tiles, 8 heads).
__global__ __launch_bounds__(256, 2) void attn_fused(
        const u16* __restrict__ Qf, const u16* __restrict__ Kf,
        const u16* __restrict__ Vtf, u16* __restrict__ E,
        float* __restrict__ lsum, float* __restrict__ ctxF, float scale) {
    __shared__ u16 lsQ[128 * 128];   // swizzled, cols 112..127 zero
    __shared__ u16 lsB[128 * 40];    // K-tile or V-tile staging (32 cols)
    __shared__ u16 lsP[128 * 128];   // swizzled e tile

    const int ks  = blockIdx.x;
    const int m0  = blockIdx.y * 128;
    const int h   = blockIdx.z;
    const int tid = threadIdx.x;
    const int lane = tid & 63, w = tid >> 6;
    const int wm = (w >> 1) * 64, wn = (w & 1) * 64;
    const int c = lane & 15, q = lane >> 4;

    // ---- stage Q tile once (128 rows x 128 cols, 112 valid, zero-padded)
    {
        const int row = tid >> 1;
        const int half = (tid & 1) * 64;
        int qrow = m0 + row; if (qrow > TP_LQ - 1) qrow = TP_LQ - 1;
        const u16* src = Qf + (size_t)qrow * TP_D + h * TP_HD;
#pragma unroll
        for (int j = 0; j < 8; ++j) {
            int col = half + j * 8;
            uint4 v = make_uint4(0, 0, 0, 0);
            if (col + 8 <= TP_HD) v = *(const uint4*)(src + col);
            *(uint4*)(&lsQ[pidx(row, col)]) = v;
        }
    }

    const int r0 = tid >> 2;
    const int c8 = (tid & 3) * 8;
    const int keybase = ks * 896;

    f32x4 acc_pv[4][4];
#pragma unroll
    for (int i = 0; i < 4; ++i)
#pragma unroll
        for (int j = 0; j < 4; ++j) acc_pv[i][j] = 0.f;
    float rs[4] = {0.f, 0.f, 0.f, 0.f};

    for (int kb = 0; kb < 7; ++kb) {
        const int kblk = keybase + kb * 128;
        f32x4 acc_s[4][4];
#pragma unroll
        for (int i = 0; i < 4; ++i)
#pragma unroll
            for (int j = 0; j < 4; ++j) acc_s[i][j] = 0.f;

        // ---- S phase: 4 kt over head dim (112, zero-padded to 128)
#pragma unroll
        for (int kt = 0; kt < 4; ++kt) {
            const int k0 = kt * 32;
            const bool valid = (k0 + c8 + 8) <= TP_HD;
            uint4 zv = make_uint4(0, 0, 0, 0);
            uint4 vb0 = valid ? *(const uint4*)(Kf + (size_t)(kblk + r0) * TP_D + h * TP_HD + k0 + c8) : zv;
            uint4 vb1 = valid ? *(const uint4*)(Kf + (size_t)(kblk + r0 + 64) * TP_D + h * TP_HD + k0 + c8) : zv;
            __syncthreads();   // protect lsB from previous consumer
            *(uint4*)(&lsB[r0 * 40 + c8])        = vb0;
            *(uint4*)(&lsB[(r0 + 64) * 40 + c8]) = vb1;
            __syncthreads();
            bf16x8 af[4], bfv[4];
#pragma unroll
            for (int mi = 0; mi < 4; ++mi)
                af[mi] = *(const bf16x8*)(&lsQ[pidx(wm + mi * 16 + c, k0 + q * 8)]);
#pragma unroll
            for (int ni = 0; ni < 4; ++ni)
                bfv[ni] = *(const bf16x8*)(&lsB[(wn + ni * 16 + c) * 40 + q * 8]);
#pragma unroll
            for (int mi = 0; mi < 4; ++mi)
#pragma unroll
                for (int ni = 0; ni < 4; ++ni)
                    acc_s[mi][ni] = __builtin_amdgcn_mfma_f32_16x16x32_bf16(bfv[ni], af[mi], acc_s[mi][ni], 0, 0, 0);
        }

        // ---- epilogue: e = exp(s*scale); store E + lsP; reg row-sums
        __syncthreads();   // previous PV reads of lsP complete
#pragma unroll
        for (int mi = 0; mi < 4; ++mi) {
            const int prow = wm + mi * 16 + c;       // query row in tile
            const int qr = m0 + prow;
            const bool qv = qr < TP_LQ;
            float rp = 0.f;
#pragma unroll
            for (int ni = 0; ni < 4; ++ni) {
                float e0, e1, e2, e3;
                {
                    f32x4 a = acc_s[mi][ni];
                    e0 = __expf(fminf(a[0] * scale, 30.f));
                    e1 = __expf(fminf(a[1] * scale, 30.f));
                    e2 = __expf(fminf(a[2] * scale, 30.f));
                    e3 = __expf(fminf(a[3] * scale, 30.f));
                }
                rp += (e0 + e1) + (e2 + e3);
                ushort4 pk = pack4(e0, e1, e2, e3);
                const int kcol = wn + ni * 16 + q * 4;
                if (qv)
                    *(ushort4*)(E + ((size_t)h * TP_LQ + qr) * TP_LK + kblk + kcol) = pk;
                *(ushort4*)(&lsP[pidx(prow, kcol)]) = pk;
            }
            rs[mi] += rp;
        }

        // ---- PV phase: 4 kt over the 128 keys of this block
#pragma unroll
        for (int kt = 0; kt < 4; ++kt) {
            const int kk = kblk + kt * 32 + c8;
            int d0 = r0;                               // < 112 always
            int d1 = r0 + 64; if (d1 > TP_HD - 1) d1 = TP_HD - 1;
            uint4 vb0 = *(const uint4*)(Vtf + ((size_t)h * TP_HD + d0) * TP_LK + kk);
            uint4 vb1 = *(const uint4*)(Vtf + ((size_t)h * TP_HD + d1) * TP_LK + kk);
            __syncthreads();   // lsB reuse; first iter: lsP writes visible
            *(uint4*)(&lsB[r0 * 40 + c8])        = vb0;
            *(uint4*)(&lsB[(r0 + 64) * 40 + c8]) = vb1;
            __syncthreads();
            bf16x8 ap[4], bv[4];
#pragma unroll
            for (int mi = 0; mi < 4; ++mi)
                ap[mi] = *(const bf16x8*)(&lsP[pidx(wm + mi * 16 + c, kt * 32 + q * 8)]);
#pragma unroll
            for (int ni = 0; ni < 4; ++ni)
                bv[ni] = *(const bf16x8*)(&lsB[(wn + ni * 16 + c) * 40 + q * 8]);
#pragma unroll
            for (int mi = 0; mi < 4; ++mi)
#pragma unroll
                for (int ni = 0; ni < 4; ++ni)
                    acc_pv[mi][ni] = __builtin_amdgcn_mfma_f32_16x16x32_bf16(ap[mi], bv[ni], acc_pv[mi][ni], 0, 0, 0);
        }
    }

    // ---- row-sum atomics (l)
#pragma unroll
    for (int mi = 0; mi < 4; ++mi) {
        float rp = rs[mi];
        rp += __shfl_xor(rp, 16, 64);
        rp += __shfl_xor(rp, 32, 64);
        const int qr = m0 + wm + mi * 16 + c;
        if (q == 0 && qr < TP_LQ) atomicAdd(&lsum[h * TP_LQ + qr], rp);
    }
    // ---- ctx atomics (normal C/D layout: col=d, rows q*4+r)
#pragma unroll
    for (int mi = 0; mi < 4; ++mi) {
#pragma unroll
        for (int r = 0; r < 4; ++r) {
            const int qr = m0 + wm + mi * 16 + q * 4 + r;
            if (qr >= TP_LQ) continue;
#pragma unroll
            for (int ni = 0; ni < 4; ++ni) {
                const int d = wn + ni * 16 + c;
                if (d < TP_HD)
                    atomicAdd(&ctxF[(size_t)qr * TP_D + h * TP_HD + d], acc_pv[mi][ni][r]);
            }
        }
    }
}

// colsum[k] += sum over rows of e[row][k]/l[row]; vec4 columns per thread
__global__ void colsum_kernel(const u16* __restrict__ E, const float* __restrict__ l,
                              float* __restrict__ colsum, int nrows) {
    int c4 = blockIdx.x * 256 + threadIdx.x;   // vec4 col index
    if (c4 >= TP_LK / 4) return;
    int chunk = (nrows + gridDim.y - 1) / gridDim.y;
    int r0 = blockIdx.y * chunk;
    int r1 = r0 + chunk; if (r1 > nrows) r1 = nrows;
    float a0 = 0.f, a1 = 0.f, a2 = 0.f, a3 = 0.f;
    for (int r = r0; r < r1; ++r) {
        float inv = 1.f / l[r];
        ushort4 u = ((const ushort4*)(E + (size_t)r * TP_LK))[c4];
        a0 += bf2f(u.x) * inv; a1 += bf2f(u.y) * inv;
        a2 += bf2f(u.z) * inv; a3 += bf2f(u.w) * inv;
    }
    atomicAdd(&colsum[4 * c4 + 0], a0);
    atomicAdd(&colsum[4 * c4 + 1], a1);
    atomicAdd(&colsum[4 * c4 + 2], a2);
    atomicAdd(&colsum[4 * c4 + 3], a3);
}

// ---------------------------------------------------------------- layernorm
// t = x + bias + res; out = LN(t)*g + b
__global__ __launch_bounds__(256) void layernorm_rows(const float* __restrict__ x,
        const float* __restrict__ bias, const float* __restrict__ res,
        const float* __restrict__ g, const float* __restrict__ b,
        float* __restrict__ outF, u16* __restrict__ outB) {
    const int tid = threadIdx.x;
    const float* xr = x + (size_t)blockIdx.x * TP_D;
    const float* rr = res + (size_t)blockIdx.x * TP_D;
    float v[4];
#pragma unroll
    for (int i = 0; i < 4; ++i) {
        int idx = tid + i * 256;
        v[i] = (idx < TP_D) ? (xr[idx] + bias[idx] + rr[idx]) : 0.f;
    }
    float s = v[0] + v[1] + v[2] + v[3];
    __shared__ float red[4];
#pragma unroll
    for (int o = 32; o > 0; o >>= 1) s += __shfl_xor(s, o, 64);
    if ((tid & 63) == 0) red[tid >> 6] = s;
    __syncthreads();
    const float mu = (red[0] + red[1] + red[2] + red[3]) * (1.f / TP_D);
    __syncthreads();
    float ss = 0.f;
#pragma unroll
    for (int i = 0; i < 4; ++i) {
        int idx = tid + i * 256;
        if (idx < TP_D) { float d = v[i] - mu; ss += d * d; }
    }
#pragma unroll
    for (int o = 32; o > 0; o >>= 1) ss += __shfl_xor(ss, o, 64);
    if ((tid & 63) == 0) red[tid >> 6] = ss;
    __syncthreads();
    const float var = (red[0] + red[1] + red[2] + red[3]) * (1.f / TP_D);
    const float rsq = rsqrtf(var + 1e-12f);
    float* of = outF + (size_t)blockIdx.x * TP_D;
    u16* obp = outB ? outB + (size_t)blockIdx.x * TP_D : nullptr;
#pragma unroll
    for (int i = 0; i < 4; ++i) {
        int idx = tid + i * 256;
        if (idx < TP_D) {
            float y = (v[i] - mu) * rsq * g[idx] + b[idx];
            of[idx] = y;
            if (obp) obp[idx] = f2bf(y);
        }
    }
}

__global__ void frame_scores_kernel(const float* __restrict__ colsum, float* __restrict__ out) {
    const int tid = threadIdx.x;
    float v = (tid < TP_P) ? colsum[blockIdx.x * TP_P + tid] : 0.f;
    __shared__ float red[4];
#pragma unroll
    for (int o = 32; o > 0; o >>= 1) v += __shfl_xor(v, o, 64);
    if ((tid & 63) == 0) red[tid >> 6] = v;
    __syncthreads();
    if (tid == 0) out[blockIdx.x] = (red[0] + red[1] + red[2] + red[3]) * (1.f / TP_P);
}

// ---------------------------------------------------------------- launch
extern "C" void kernel_launch(void* const* d_in, const int* in_sizes, int n_in,
                              void* d_out, int out_size, void* d_ws, size_t ws_size,
                              hipStream_t stream) {
    const float* img  = (const float*)d_in[0];
    const float* mem  = (const float*)d_in[1];
    const float* qW   = (const float*)d_in[2];
    const float* qb   = (const float*)d_in[3];
    const float* kW   = (const float*)d_in[4];
    const float* kb   = (const float*)d_in[5];
    const float* vW   = (const float*)d_in[6];
    const float* vb   = (const float*)d_in[7];
    const float* oW   = (const float*)d_in[8];
    const float* ob   = (const float*)d_in[9];
    const float* ln1g = (const float*)d_in[10];
    const float* ln1b = (const float*)d_in[11];
    const float* mW   = (const float*)d_in[12];
    const float* mb   = (const float*)d_in[13];
    const float* pW   = (const float*)d_in[14];
    const float* pb   = (const float*)d_in[15];
    const float* ln2g = (const float*)d_in[16];
    const float* ln2b = (const float*)d_in[17];
    float* out = (float*)d_out;

    char* base = (char*)d_ws;
    size_t off = 0;
    auto take = [&](size_t nbytes) -> void* {
        void* p = base + off;
        off += (nbytes + 255) & ~(size_t)255;
        return p;
    };

    u16* imgB  = (u16*)take((size_t)TP_LK * TP_D * 2);
    u16* memB  = (u16*)take((size_t)TP_LQ * TP_D * 2);
    u16* qWt   = (u16*)take((size_t)TP_D * TP_D * 2);
    u16* kWt   = (u16*)take((size_t)TP_D * TP_D * 2);
    u16* vWt   = (u16*)take((size_t)TP_D * TP_D * 2);
    u16* oWt   = (u16*)take((size_t)TP_D * TP_D * 2);
    u16* mWt   = (u16*)take((size_t)TP_D * TP_D4 * 2);
    u16* pWt   = (u16*)take((size_t)TP_D * TP_D4 * 2);
    u16* Qf    = (u16*)take((size_t)TP_LQ * TP_D * 2);
    u16* Kf    = (u16*)take((size_t)TP_LK * TP_D * 2);
    u16* Vtf   = (u16*)take((size_t)TP_LK * TP_D * 2);
    u16* ctxB  = (u16*)take((size_t)TP_LQ * TP_D * 2);
    float* attn  = (float*)take((size_t)TP_LQ * TP_D * 4);
    u16* attnB = (u16*)take((size_t)TP_LQ * TP_D * 2);
    u16* hidden= (u16*)take((size_t)TP_LQ * TP_D4 * 2);
    u16* E     = (u16*)take((size_t)TP_H * TP_LQ * TP_LK * 2);
    // ---- contiguous zero region (single memset) ----
    float* ctxF  = (float*)take((size_t)TP_LQ * TP_D * 4);
    float* pre1  = (float*)take((size_t)TP_LQ * TP_D * 4);
    float* pre2  = (float*)take((size_t)TP_LQ * TP_D * 4);
    float* colsum= (float*)take((size_t)TP_LK * 4);
    float* lsum  = (float*)take((size_t)TP_H * TP_LQ * 4);
    size_t zlen = (char*)(lsum + TP_H * TP_LQ) - (char*)ctxF;

    // ---- casts / transposes / zero-init
    {
        int n0 = TP_LK * TP_D, n1 = TP_LQ * TP_D;
        cast2_f32_bf16<<<((n0 + n1) / 4 + 255) / 256, 256, 0, stream>>>(img, imgB, n0, mem, memB, n1);
    }
    transpose_cast4<<<dim3(28, 28, 4), dim3(32, 8), 0, stream>>>(qW, qWt, kW, kWt, vW, vWt, oW, oWt);
    transpose_cast<<<dim3(TP_D4 / 32, TP_D / 32), dim3(32, 8), 0, stream>>>(mW, mWt, TP_D, TP_D4);
    transpose_cast<<<dim3(TP_D / 32, TP_D4 / 32), dim3(32, 8), 0, stream>>>(pW, pWt, TP_D4, TP_D);
    hipMemsetAsync(ctxF, 0, zlen, stream);

    // ---- QKV projections in one dispatch (z: 0=K, 1=V^T, 2=Q)
    qkv_proj<<<dim3(14, 49, 3), 256, 0, stream>>>(imgB, memB, kWt, vWt, qWt,
                                                  kb, vb, qb, Kf, Vtf, Qf);

    // ---- fused attention (S + exp + E + l + PV), colsum over E, normalize
    const float scale = 0.09449111825230679f;  // 1/sqrt(112)
    attn_fused<<<dim3(7, 13, TP_H), 256, 0, stream>>>(Qf, Kf, Vtf, E, lsum, ctxF, scale);
    colsum_kernel<<<dim3(7, 448), 256, 0, stream>>>(E, lsum, colsum, TP_H * TP_LQ);
    cast_div_bf16<<<(TP_LQ * TP_D / 4 + 255) / 256, 256, 0, stream>>>(ctxF, lsum, ctxB);

    // ---- O-projection split-K x2 -> pre1 (bias+residual in LN1)
    {
        GemmParams p{};
        p.A = ctxB; p.lda = TP_D;
        p.Bt = oWt; p.ldb = TP_D;
        p.M = TP_LQ; p.N = TP_D; p.K = 448; p.kc = 448;
        p.outF = pre1; p.ldc = TP_D;
        gemm_bf16<6, 2><<<dim3(14, 13, 2), 256, 0, stream>>>(p);
    }
    layernorm_rows<<<TP_LQ, 256, 0, stream>>>(pre1, ob, mem, ln1g, ln1b, attn, attnB);

    // ---- MLP
    {
        GemmParams p{};
        p.A = attnB; p.lda = TP_D;
        p.Bt = mWt; p.ldb = TP_D;
        p.M = TP_LQ; p.N = TP_D4; p.K = TP_D;
        p.bias = mb; p.outB = hidden; p.ldc = TP_D4; p.relu = 1;
        gemm_bf16<4, 2><<<dim3(56, 13, 1), 256, 0, stream>>>(p);
    }
    {   // MLP2 split-K x4 -> pre2 (bias+residual in LN2)
        GemmParams p{};
        p.A = hidden; p.lda = TP_D4;
        p.Bt = pWt; p.ldb = TP_D4;
        p.M = TP_LQ; p.N = TP_D; p.K = 896; p.kc = 896;
        p.outF = pre2; p.ldc = TP_D;
        gemm_bf16<6, 2><<<dim3(14, 13, 4), 256, 0, stream>>>(p);
    }
    layernorm_rows<<<TP_LQ, 256, 0, stream>>>(pre2, pb, attn, ln2g, ln2b, out, nullptr);

    // ---- frame scores
    frame_scores_kernel<<<TP_F, 256, 0, stream>>>(colsum, out + (size_t)TP_LQ * TP_D);
}

// Round 11
// 498.494 us; speedup vs baseline: 1.3272x; 1.0389x over previous
//
#include <hip/hip_runtime.h>
#include <hip/hip_bf16.h>
#include <math.h>

#define TP_D   896
#define TP_H   8
#define TP_HD  112
#define TP_LQ  1568
#define TP_LK  6272
#define TP_D4  3584
#define TP_F   32
#define TP_P   196

typedef unsigned short u16;
typedef float f32x4 __attribute__((ext_vector_type(4)));
typedef __bf16 bf16x8 __attribute__((ext_vector_type(8)));

__device__ inline float bf2f(u16 u) {
    return __uint_as_float(((unsigned int)u) << 16);
}
__device__ inline u16 f2bf(float f) {
    unsigned int x = __float_as_uint(f);
    unsigned int lsb = (x >> 16) & 1u;
    x += 0x7fffu + lsb;
    return (u16)(x >> 16);
}
__device__ inline ushort4 pack4(float a, float b, float c, float d) {
    return make_ushort4(f2bf(a), f2bf(b), f2bf(c), f2bf(d));
}
// XOR-swizzled 128-col LDS tile index (16B-block swizzle) — attn only
__device__ inline int pidx(int row, int col) {
    return row * 128 + (col ^ ((row & 7) << 3));
}
// async global->LDS, 16B per lane, lands at ldsbase + lane*16
__device__ inline void gl_lds16(const u16* g, u16* l) {
    __builtin_amdgcn_global_load_lds(
        (const __attribute__((address_space(1))) unsigned int*)g,
        (__attribute__((address_space(3))) unsigned int*)l,
        16, 0, 0);
}

// ---------------------------------------------------------------- casts
// two arrays in one dispatch: [src0, n0) then [src1, n1)
__global__ void cast2_f32_bf16(const float* __restrict__ src0, u16* __restrict__ dst0, int n0,
                               const float* __restrict__ src1, u16* __restrict__ dst1, int n1) {
    int i = (blockIdx.x * blockDim.x + threadIdx.x) * 4;
    const float* s; u16* d; int n;
    if (i < n0) { s = src0; d = dst0; n = n0; }
    else        { i -= n0; s = src1; d = dst1; n = n1; if (i >= n) return; }
    float4 v = *(const float4*)(s + i);
    *(ushort4*)(d + i) = pack4(v.x, v.y, v.z, v.w);
}

// ctx fp32 (atomic-accumulated e*V) -> /l -> bf16
__global__ void cast_div_bf16(const float* __restrict__ src, const float* __restrict__ l,
                              u16* __restrict__ dst) {
    int i = (blockIdx.x * 256 + threadIdx.x) * 4;
    if (i >= TP_LQ * TP_D) return;
    int q = i / TP_D;
    int col = i - q * TP_D;
    int h = col / TP_HD;
    float inv = 1.f / l[h * TP_LQ + q];
    float4 v = *(const float4*)(src + i);
    *(ushort4*)(dst + i) = pack4(v.x * inv, v.y * inv, v.z * inv, v.w * inv);
}

// src fp32 [R][C] -> dst bf16 [C][R].  R,C multiples of 32. block (32,8)
__global__ void transpose_cast(const float* __restrict__ src, u16* __restrict__ dst, int R, int C) {
    __shared__ float t[32][33];
    int bx = blockIdx.x * 32;
    int by = blockIdx.y * 32;
    int tx = threadIdx.x, ty = threadIdx.y;
#pragma unroll
    for (int j = 0; j < 4; ++j)
        t[ty + j * 8][tx] = src[(size_t)(by + ty + j * 8) * C + bx + tx];
    __syncthreads();
#pragma unroll
    for (int j = 0; j < 4; ++j)
        dst[(size_t)(bx + ty + j * 8) * R + by + tx] = f2bf(t[tx][ty + j * 8]);
}

// four 896x896 transposes in one dispatch (z selects)
__global__ void transpose_cast4(const float* __restrict__ s0, u16* __restrict__ d0,
                                const float* __restrict__ s1, u16* __restrict__ d1,
                                const float* __restrict__ s2, u16* __restrict__ d2,
                                const float* __restrict__ s3, u16* __restrict__ d3) {
    __shared__ float t[32][33];
    const float* src; u16* dst;
    switch (blockIdx.z) {
        case 0: src = s0; dst = d0; break;
        case 1: src = s1; dst = d1; break;
        case 2: src = s2; dst = d2; break;
        default: src = s3; dst = d3; break;
    }
    int bx = blockIdx.x * 32;
    int by = blockIdx.y * 32;
    int tx = threadIdx.x, ty = threadIdx.y;
#pragma unroll
    for (int j = 0; j < 4; ++j)
        t[ty + j * 8][tx] = src[(size_t)(by + ty + j * 8) * TP_D + bx + tx];
    __syncthreads();
#pragma unroll
    for (int j = 0; j < 4; ++j)
        dst[(size_t)(bx + ty + j * 8) * TP_D + by + tx] = f2bf(t[tx][ty + j * 8]);
}

// ---------------------------------------------------------------- GEMM
// C[M,N] = A[M,K] @ Bt[N,K]^T, tile 128m x 64n, BK=32, global_load_lds staging.
// LDS layout (chunk-swizzled): elem(row, chunk=col8/8) at row*32 + ((chunk^(row&3))<<3).
// DMA: lane λ lands at base+λ*16 = (λ>>2)-th row, phys chunk λ&3 -> fetch logical
// chunk (λ&3)^((λ>>2)&3).  Requires K % 32 == 0 (all users satisfy).
// MODE 4: out bf16 = acc + bias[col] (relu optional)
// MODE 6: split-K: z = k-slice (chunk p.kc); atomicAdd fp32 into outF
struct GemmParams {
    const u16* A;  int lda;
    const u16* Bt; int ldb;
    int M, N, K;
    const float* bias;
    float* outF;
    u16* outB; int ldc;
    int relu;
    int kc;
};

template <int MODE>
__global__ __launch_bounds__(256, 4) void gemm_bf16(GemmParams p) {
    __shared__ u16 lsA[128 * 32];   // 8 KB
    __shared__ u16 lsB[64 * 32];    // 4 KB

    const int tid = threadIdx.x;
    const int z = blockIdx.z;
    const u16* A  = p.A;
    const u16* Bt = p.Bt;
    if (MODE == 6) {
        A  += (size_t)z * p.kc;
        Bt += (size_t)z * p.kc;
    }
    const int m0 = blockIdx.y * 128;
    const int n0 = blockIdx.x * 64;

    const int lane = tid & 63;
    const int w = tid >> 6;
    const int wm = (w >> 1) * 64, wn = (w & 1) * 32;
    const int c = lane & 15, q = lane >> 4;
    const int xq = (q ^ (c & 3)) << 3;     // swizzled chunk offset for reads

    f32x4 acc[4][2];
#pragma unroll
    for (int i = 0; i < 4; ++i) { acc[i][0] = 0.f; acc[i][1] = 0.f; }

    // staging geometry
    const int lrow = lane >> 2;                        // 0..15
    const int lchunk = (lane & 3) ^ (lrow & 3);        // logical chunk to fetch
    int ga_row0 = m0 + w * 32 + lrow;      if (ga_row0 >= p.M) ga_row0 = p.M - 1;
    int ga_row1 = m0 + w * 32 + 16 + lrow; if (ga_row1 >= p.M) ga_row1 = p.M - 1;
    int gb_row  = n0 + w * 16 + lrow;      if (gb_row  >= p.N) gb_row  = p.N - 1;
    const u16* gA0 = A  + (size_t)ga_row0 * p.lda + lchunk * 8;
    const u16* gA1 = A  + (size_t)ga_row1 * p.lda + lchunk * 8;
    const u16* gB  = Bt + (size_t)gb_row  * p.ldb + lchunk * 8;
    u16* lA0 = &lsA[(w * 32) * 32];
    u16* lA1 = &lsA[(w * 32 + 16) * 32];
    u16* lB  = &lsB[(w * 16) * 32];

    const int KT = p.K >> 5;
    for (int kt = 0; kt < KT; ++kt) {
        const int k0 = kt << 5;
        gl_lds16(gA0 + k0, lA0);
        gl_lds16(gA1 + k0, lA1);
        gl_lds16(gB + k0, lB);
        __syncthreads();   // drains DMA (vmcnt) + prior reads done

        bf16x8 af[4], bfv[2];
#pragma unroll
        for (int mi = 0; mi < 4; ++mi) {
            const int r = wm + mi * 16 + c;
            af[mi] = *(const bf16x8*)(&lsA[r * 32 + xq]);
        }
#pragma unroll
        for (int ni = 0; ni < 2; ++ni) {
            const int rb = wn + ni * 16 + c;
            bfv[ni] = *(const bf16x8*)(&lsB[rb * 32 + xq]);
        }
#pragma unroll
        for (int mi = 0; mi < 4; ++mi)
#pragma unroll
            for (int ni = 0; ni < 2; ++ni)
                acc[mi][ni] = __builtin_amdgcn_mfma_f32_16x16x32_bf16(af[mi], bfv[ni], acc[mi][ni], 0, 0, 0);
        __syncthreads();
    }

#pragma unroll
    for (int mi = 0; mi < 4; ++mi) {
#pragma unroll
        for (int r = 0; r < 4; ++r) {
            const int row = m0 + wm + mi * 16 + q * 4 + r;
            if (row >= p.M) continue;
#pragma unroll
            for (int ni = 0; ni < 2; ++ni) {
                const int col = n0 + wn + ni * 16 + c;
                float v = acc[mi][ni][r];
                if (MODE == 4) {
                    v += p.bias[col];
                    if (p.relu) v = v > 0.f ? v : 0.f;
                    p.outB[(size_t)row * p.ldc + col] = f2bf(v);
                } else if (MODE == 6) {
                    atomicAdd(&p.outF[(size_t)row * p.ldc + col], v);
                }
            }
        }
    }
}

// ---------------------------------------------------------------- QKV projection
// One dispatch, z in {0:K-proj, 1:V-proj (writes V^T), 2:Q-proj}.
// Same global_load_lds staging as gemm_bf16; K = 896.
__global__ __launch_bounds__(256, 4) void qkv_proj(
        const u16* __restrict__ imgB, const u16* __restrict__ memB,
        const u16* __restrict__ kWt, const u16* __restrict__ vWt, const u16* __restrict__ qWt,
        const float* __restrict__ kb, const float* __restrict__ vb, const float* __restrict__ qb,
        u16* __restrict__ Kf, u16* __restrict__ Vtf, u16* __restrict__ Qf) {
    __shared__ u16 lsA[128 * 32];
    __shared__ u16 lsB[64 * 32];

    const int z = blockIdx.z;
    const u16* A; const u16* Bt; const float* bias; int M;
    if (z == 0)      { A = imgB; Bt = kWt; bias = kb; M = TP_LK; }
    else if (z == 1) { A = imgB; Bt = vWt; bias = vb; M = TP_LK; }
    else             { A = memB; Bt = qWt; bias = qb; M = TP_LQ; }

    const int m0 = blockIdx.y * 128;
    if (m0 >= M) return;
    const int n0 = blockIdx.x * 64;

    const int tid = threadIdx.x;
    const int lane = tid & 63;
    const int w = tid >> 6;
    const int wm = (w >> 1) * 64, wn = (w & 1) * 32;
    const int c = lane & 15, q = lane >> 4;
    const int xq = (q ^ (c & 3)) << 3;

    f32x4 acc[4][2];
#pragma unroll
    for (int i = 0; i < 4; ++i) { acc[i][0] = 0.f; acc[i][1] = 0.f; }

    const int lrow = lane >> 2;
    const int lchunk = (lane & 3) ^ (lrow & 3);
    int ga_row0 = m0 + w * 32 + lrow;      if (ga_row0 >= M) ga_row0 = M - 1;
    int ga_row1 = m0 + w * 32 + 16 + lrow; if (ga_row1 >= M) ga_row1 = M - 1;
    const int gb_row = n0 + w * 16 + lrow;    // N = 896 exact
    const u16* gA0 = A  + (size_t)ga_row0 * TP_D + lchunk * 8;
    const u16* gA1 = A  + (size_t)ga_row1 * TP_D + lchunk * 8;
    const u16* gB  = Bt + (size_t)gb_row  * TP_D + lchunk * 8;
    u16* lA0 = &lsA[(w * 32) * 32];
    u16* lA1 = &lsA[(w * 32 + 16) * 32];
    u16* lB  = &lsB[(w * 16) * 32];

    for (int kt = 0; kt < 28; ++kt) {
        const int k0 = kt << 5;
        gl_lds16(gA0 + k0, lA0);
        gl_lds16(gA1 + k0, lA1);
        gl_lds16(gB + k0, lB);
        __syncthreads();

        bf16x8 af[4], bfv[2];
#pragma unroll
        for (int mi = 0; mi < 4; ++mi) {
            const int r = wm + mi * 16 + c;
            af[mi] = *(const bf16x8*)(&lsA[r * 32 + xq]);
        }
#pragma unroll
        for (int ni = 0; ni < 2; ++ni) {
            const int rb = wn + ni * 16 + c;
            bfv[ni] = *(const bf16x8*)(&lsB[rb * 32 + xq]);
        }
#pragma unroll
        for (int mi = 0; mi < 4; ++mi)
#pragma unroll
            for (int ni = 0; ni < 2; ++ni)
                acc[mi][ni] = __builtin_amdgcn_mfma_f32_16x16x32_bf16(af[mi], bfv[ni], acc[mi][ni], 0, 0, 0);
        __syncthreads();
    }

    if (z == 1) {
        // V^T epilogue: lane regs = 4 consecutive rows, contiguous along V^T inner dim
#pragma unroll
        for (int ni = 0; ni < 2; ++ni) {
            const int col = n0 + wn + ni * 16 + c;
            const float bv = bias[col];
#pragma unroll
            for (int mi = 0; mi < 4; ++mi) {
                const int mbase = m0 + wm + mi * 16 + q * 4;
                f32x4 a = acc[mi][ni];
                *(ushort4*)(Vtf + (size_t)col * TP_LK + mbase) =
                    pack4(a[0] + bv, a[1] + bv, a[2] + bv, a[3] + bv);
            }
        }
        return;
    }

    u16* outB = (z == 0) ? Kf : Qf;
#pragma unroll
    for (int mi = 0; mi < 4; ++mi) {
#pragma unroll
        for (int r = 0; r < 4; ++r) {
            const int row = m0 + wm + mi * 16 + q * 4 + r;
            if (row >= M) continue;
#pragma unroll
            for (int ni = 0; ni < 2; ++ni) {
                const int col = n0 + wn + ni * 16 + c;
                outB[(size_t)row * TP_D + col] = f2bf(acc[mi][ni][r] + bias[col]);
            }
        }
    }
}

// ---------------------------------------------------------------- fused attention
// R8-verbatim (measured 150 us): grid (7 k-chunks, 13 q-tiles, 8 heads).
__global__ __launch_bounds__(256, 2) void attn_fused(
        const u16* __restrict__ Qf, const u16* __restrict__ Kf,
        const u16* __restrict__ Vtf, u16* __restrict__ E,
        float* __restrict__ lsum, float* __restrict__ ctxF, float scale) {
    __shared__ u16 lsQ[128 * 128];   // swizzled, cols 112..127 zero
    __shared__ u16 lsB[128 * 40];    // K-tile or V-tile staging (32 cols)
    __shared__ u16 lsP[128 * 128];   // swizzled e tile

    const int ks  = blockIdx.x;
    const int m0  = blockIdx.y * 128;
    const int h   = blockIdx.z;
    const int tid = threadIdx.x;
    const int lane = tid & 63, w = tid >> 6;
    const int wm = (w >> 1) * 64, wn = (w & 1) * 64;
    const int c = lane & 15, q = lane >> 4;

    // ---- stage Q tile once (128 rows x 128 cols, 112 valid, zero-padded)
    {
        const int row = tid >> 1;
        const int half = (tid & 1) * 64;
        int qrow = m0 + row; if (qrow > TP_LQ - 1) qrow = TP_LQ - 1;
        const u16* src = Qf + (size_t)qrow * TP_D + h * TP_HD;
#pragma unroll
        for (int j = 0; j < 8; ++j) {
            int col = half + j * 8;
            uint4 v = make_uint4(0, 0, 0, 0);
            if (col + 8 <= TP_HD) v = *(const uint4*)(src + col);
            *(uint4*)(&lsQ[pidx(row, col)]) = v;
        }
    }

    const int r0 = tid >> 2;
    const int c8 = (tid & 3) * 8;
    const int keybase = ks * 896;

    f32x4 acc_pv[4][4];
#pragma unroll
    for (int i = 0; i < 4; ++i)
#pragma unroll
        for (int j = 0; j < 4; ++j) acc_pv[i][j] = 0.f;
    float rs[4] = {0.f, 0.f, 0.f, 0.f};

    for (int kb = 0; kb < 7; ++kb) {
        const int kblk = keybase + kb * 128;
        f32x4 acc_s[4][4];
#pragma unroll
        for (int i = 0; i < 4; ++i)
#pragma unroll
            for (int j = 0; j < 4; ++j) acc_s[i][j] = 0.f;

        // ---- S phase: 4 kt over head dim (112, zero-padded to 128)
#pragma unroll
        for (int kt = 0; kt < 4; ++kt) {
            const int k0 = kt * 32;
            const bool valid = (k0 + c8 + 8) <= TP_HD;
            uint4 zv = make_uint4(0, 0, 0, 0);
            uint4 vb0 = valid ? *(const uint4*)(Kf + (size_t)(kblk + r0) * TP_D + h * TP_HD + k0 + c8) : zv;
            uint4 vb1 = valid ? *(const uint4*)(Kf + (size_t)(kblk + r0 + 64) * TP_D + h * TP_HD + k0 + c8) : zv;
            __syncthreads();   // protect lsB from previous consumer
            *(uint4*)(&lsB[r0 * 40 + c8])        = vb0;
            *(uint4*)(&lsB[(r0 + 64) * 40 + c8]) = vb1;
            __syncthreads();
            bf16x8 af[4], bfv[4];
#pragma unroll
            for (int mi = 0; mi < 4; ++mi)
                af[mi] = *(const bf16x8*)(&lsQ[pidx(wm + mi * 16 + c, k0 + q * 8)]);
#pragma unroll
            for (int ni = 0; ni < 4; ++ni)
                bfv[ni] = *(const bf16x8*)(&lsB[(wn + ni * 16 + c) * 40 + q * 8]);
#pragma unroll
            for (int mi = 0; mi < 4; ++mi)
#pragma unroll
                for (int ni = 0; ni < 4; ++ni)
                    acc_s[mi][ni] = __builtin_amdgcn_mfma_f32_16x16x32_bf16(bfv[ni], af[mi], acc_s[mi][ni], 0, 0, 0);
        }

        // ---- epilogue: e = exp(s*scale); store E + lsP; reg row-sums
        __syncthreads();   // previous PV reads of lsP complete
#pragma unroll
        for (int mi = 0; mi < 4; ++mi) {
            const int prow = wm + mi * 16 + c;       // query row in tile
            const int qr = m0 + prow;
            const bool qv = qr < TP_LQ;
            float rp = 0.f;
#pragma unroll
            for (int ni = 0; ni < 4; ++ni) {
                float e0, e1, e2, e3;
                {
                    f32x4 a = acc_s[mi][ni];
                    e0 = __expf(fminf(a[0] * scale, 30.f));
                    e1 = __expf(fminf(a[1] * scale, 30.f));
                    e2 = __expf(fminf(a[2] * scale, 30.f));
                    e3 = __expf(fminf(a[3] * scale, 30.f));
                }
                rp += (e0 + e1) + (e2 + e3);
                ushort4 pk = pack4(e0, e1, e2, e3);
                const int kcol = wn + ni * 16 + q * 4;
                if (qv)
                    *(ushort4*)(E + ((size_t)h * TP_LQ + qr) * TP_LK + kblk + kcol) = pk;
                *(ushort4*)(&lsP[pidx(prow, kcol)]) = pk;
            }
            rs[mi] += rp;
        }

        // ---- PV phase: 4 kt over the 128 keys of this block
#pragma unroll
        for (int kt = 0; kt < 4; ++kt) {
            const int kk = kblk + kt * 32 + c8;
            int d0 = r0;                               // < 112 always
            int d1 = r0 + 64; if (d1 > TP_HD - 1) d1 = TP_HD - 1;
            uint4 vb0 = *(const uint4*)(Vtf + ((size_t)h * TP_HD + d0) * TP_LK + kk);
            uint4 vb1 = *(const uint4*)(Vtf + ((size_t)h * TP_HD + d1) * TP_LK + kk);
            __syncthreads();   // lsB reuse; first iter: lsP writes visible
            *(uint4*)(&lsB[r0 * 40 + c8])        = vb0;
            *(uint4*)(&lsB[(r0 + 64) * 40 + c8]) = vb1;
            __syncthreads();
            bf16x8 ap[4], bv[4];
#pragma unroll
            for (int mi = 0; mi < 4; ++mi)
                ap[mi] = *(const bf16x8*)(&lsP[pidx(wm + mi * 16 + c, kt * 32 + q * 8)]);
#pragma unroll
            for (int ni = 0; ni < 4; ++ni)
                bv[ni] = *(const bf16x8*)(&lsB[(wn + ni * 16 + c) * 40 + q * 8]);
#pragma unroll
            for (int mi = 0; mi < 4; ++mi)
#pragma unroll
                for (int ni = 0; ni < 4; ++ni)
                    acc_pv[mi][ni] = __builtin_amdgcn_mfma_f32_16x16x32_bf16(ap[mi], bv[ni], acc_pv[mi][ni], 0, 0, 0);
        }
    }

    // ---- row-sum atomics (l)
#pragma unroll
    for (int mi = 0; mi < 4; ++mi) {
        float rp = rs[mi];
        rp += __shfl_xor(rp, 16, 64);
        rp += __shfl_xor(rp, 32, 64);
        const int qr = m0 + wm + mi * 16 + c;
        if (q == 0 && qr < TP_LQ) atomicAdd(&lsum[h * TP_LQ + qr], rp);
    }
    // ---- ctx atomics (normal C/D layout: col=d, rows q*4+r)
#pragma unroll
    for (int mi = 0; mi < 4; ++mi) {
#pragma unroll
        for (int r = 0; r < 4; ++r) {
            const int qr = m0 + wm + mi * 16 + q * 4 + r;
            if (qr >= TP_LQ) continue;
#pragma unroll
            for (int ni = 0; ni < 4; ++ni) {
                const int d = wn + ni * 16 + c;
                if (d < TP_HD)
                    atomicAdd(&ctxF[(size_t)qr * TP_D + h * TP_HD + d], acc_pv[mi][ni][r]);
            }
        }
    }
}

// colsum[k] += sum over rows of e[row][k]/l[row]; vec4 columns per thread
__global__ void colsum_kernel(const u16* __restrict__ E, const float* __restrict__ l,
                              float* __restrict__ colsum, int nrows) {
    int c4 = blockIdx.x * 256 + threadIdx.x;   // vec4 col index
    if (c4 >= TP_LK / 4) return;
    int chunk = (nrows + gridDim.y - 1) / gridDim.y;
    int r0 = blockIdx.y * chunk;
    int r1 = r0 + chunk; if (r1 > nrows) r1 = nrows;
    float a0 = 0.f, a1 = 0.f, a2 = 0.f, a3 = 0.f;
    for (int r = r0; r < r1; ++r) {
        float inv = 1.f / l[r];
        ushort4 u = ((const ushort4*)(E + (size_t)r * TP_LK))[c4];
        a0 += bf2f(u.x) * inv; a1 += bf2f(u.y) * inv;
        a2 += bf2f(u.z) * inv; a3 += bf2f(u.w) * inv;
    }
    atomicAdd(&colsum[4 * c4 + 0], a0);
    atomicAdd(&colsum[4 * c4 + 1], a1);
    atomicAdd(&colsum[4 * c4 + 2], a2);
    atomicAdd(&colsum[4 * c4 + 3], a3);
}

// ---------------------------------------------------------------- layernorm
// t = x + bias + res; out = LN(t)*g + b
__global__ __launch_bounds__(256) void layernorm_rows(const float* __restrict__ x,
        const float* __restrict__ bias, const float* __restrict__ res,
        const float* __restrict__ g, const float* __restrict__ b,
        float* __restrict__ outF, u16* __restrict__ outB) {
    const int tid = threadIdx.x;
    const float* xr = x + (size_t)blockIdx.x * TP_D;
    const float* rr = res + (size_t)blockIdx.x * TP_D;
    float v[4];
#pragma unroll
    for (int i = 0; i < 4; ++i) {
        int idx = tid + i * 256;
        v[i] = (idx < TP_D) ? (xr[idx] + bias[idx] + rr[idx]) : 0.f;
    }
    float s = v[0] + v[1] + v[2] + v[3];
    __shared__ float red[4];
#pragma unroll
    for (int o = 32; o > 0; o >>= 1) s += __shfl_xor(s, o, 64);
    if ((tid & 63) == 0) red[tid >> 6] = s;
    __syncthreads();
    const float mu = (red[0] + red[1] + red[2] + red[3]) * (1.f / TP_D);
    __syncthreads();
    float ss = 0.f;
#pragma unroll
    for (int i = 0; i < 4; ++i) {
        int idx = tid + i * 256;
        if (idx < TP_D) { float d = v[i] - mu; ss += d * d; }
    }
#pragma unroll
    for (int o = 32; o > 0; o >>= 1) ss += __shfl_xor(ss, o, 64);
    if ((tid & 63) == 0) red[tid >> 6] = ss;
    __syncthreads();
    const float var = (red[0] + red[1] + red[2] + red[3]) * (1.f / TP_D);
    const float rsq = rsqrtf(var + 1e-12f);
    float* of = outF + (size_t)blockIdx.x * TP_D;
    u16* obp = outB ? outB + (size_t)blockIdx.x * TP_D : nullptr;
#pragma unroll
    for (int i = 0; i < 4; ++i) {
        int idx = tid + i * 256;
        if (idx < TP_D) {
            float y = (v[i] - mu) * rsq * g[idx] + b[idx];
            of[idx] = y;
            if (obp) obp[idx] = f2bf(y);
        }
    }
}

__global__ void frame_scores_kernel(const float* __restrict__ colsum, float* __restrict__ out) {
    const int tid = threadIdx.x;
    float v = (tid < TP_P) ? colsum[blockIdx.x * TP_P + tid] : 0.f;
    __shared__ float red[4];
#pragma unroll
    for (int o = 32; o > 0; o >>= 1) v += __shfl_xor(v, o, 64);
    if ((tid & 63) == 0) red[tid >> 6] = v;
    __syncthreads();
    if (tid == 0) out[blockIdx.x] = (red[0] + red[1] + red[2] + red[3]) * (1.f / TP_P);
}

// ---------------------------------------------------------------- launch
extern "C" void kernel_launch(void* const* d_in, const int* in_sizes, int n_in,
                              void* d_out, int out_size, void* d_ws, size_t ws_size,
                              hipStream_t stream) {
    const float* img  = (const float*)d_in[0];
    const float* mem  = (const float*)d_in[1];
    const float* qW   = (const float*)d_in[2];
    const float* qb   = (const float*)d_in[3];
    const float* kW   = (const float*)d_in[4];
    const float* kb   = (const float*)d_in[5];
    const float* vW   = (const float*)d_in[6];
    const float* vb   = (const float*)d_in[7];
    const float* oW   = (const float*)d_in[8];
    const float* ob   = (const float*)d_in[9];
    const float* ln1g = (const float*)d_in[10];
    const float* ln1b = (const float*)d_in[11];
    const float* mW   = (const float*)d_in[12];
    const float* mb   = (const float*)d_in[13];
    const float* pW   = (const float*)d_in[14];
    const float* pb   = (const float*)d_in[15];
    const float* ln2g = (const float*)d_in[16];
    const float* ln2b = (const float*)d_in[17];
    float* out = (float*)d_out;

    char* base = (char*)d_ws;
    size_t off = 0;
    auto take = [&](size_t nbytes) -> void* {
        void* p = base + off;
        off += (nbytes + 255) & ~(size_t)255;
        return p;
    };

    u16* imgB  = (u16*)take((size_t)TP_LK * TP_D * 2);
    u16* memB  = (u16*)take((size_t)TP_LQ * TP_D * 2);
    u16* qWt   = (u16*)take((size_t)TP_D * TP_D * 2);
    u16* kWt   = (u16*)take((size_t)TP_D * TP_D * 2);
    u16* vWt   = (u16*)take((size_t)TP_D * TP_D * 2);
    u16* oWt   = (u16*)take((size_t)TP_D * TP_D * 2);
    u16* mWt   = (u16*)take((size_t)TP_D * TP_D4 * 2);
    u16* pWt   = (u16*)take((size_t)TP_D * TP_D4 * 2);
    u16* Qf    = (u16*)take((size_t)TP_LQ * TP_D * 2);
    u16* Kf    = (u16*)take((size_t)TP_LK * TP_D * 2);
    u16* Vtf   = (u16*)take((size_t)TP_LK * TP_D * 2);
    u16* ctxB  = (u16*)take((size_t)TP_LQ * TP_D * 2);
    float* attn  = (float*)take((size_t)TP_LQ * TP_D * 4);
    u16* attnB = (u16*)take((size_t)TP_LQ * TP_D * 2);
    u16* hidden= (u16*)take((size_t)TP_LQ * TP_D4 * 2);
    u16* E     = (u16*)take((size_t)TP_H * TP_LQ * TP_LK * 2);
    // ---- contiguous zero region (single memset) ----
    float* ctxF  = (float*)take((size_t)TP_LQ * TP_D * 4);
    float* pre1  = (float*)take((size_t)TP_LQ * TP_D * 4);
    float* pre2  = (float*)take((size_t)TP_LQ * TP_D * 4);
    float* colsum= (float*)take((size_t)TP_LK * 4);
    float* lsum  = (float*)take((size_t)TP_H * TP_LQ * 4);
    size_t zlen = (char*)(lsum + TP_H * TP_LQ) - (char*)ctxF;

    // ---- casts / transposes / zero-init
    {
        int n0 = TP_LK * TP_D, n1 = TP_LQ * TP_D;
        cast2_f32_bf16<<<((n0 + n1) / 4 + 255) / 256, 256, 0, stream>>>(img, imgB, n0, mem, memB, n1);
    }
    transpose_cast4<<<dim3(28, 28, 4), dim3(32, 8), 0, stream>>>(qW, qWt, kW, kWt, vW, vWt, oW, oWt);
    transpose_cast<<<dim3(TP_D4 / 32, TP_D / 32), dim3(32, 8), 0, stream>>>(mW, mWt, TP_D, TP_D4);
    transpose_cast<<<dim3(TP_D / 32, TP_D4 / 32), dim3(32, 8), 0, stream>>>(pW, pWt, TP_D4, TP_D);
    hipMemsetAsync(ctxF, 0, zlen, stream);

    // ---- QKV projections in one dispatch (z: 0=K, 1=V^T, 2=Q)
    qkv_proj<<<dim3(14, 49, 3), 256, 0, stream>>>(imgB, memB, kWt, vWt, qWt,
                                                  kb, vb, qb, Kf, Vtf, Qf);

    // ---- fused attention (S + exp + E + l + PV), colsum over E, normalize
    const float scale = 0.09449111825230679f;  // 1/sqrt(112)
    attn_fused<<<dim3(7, 13, TP_H), 256, 0, stream>>>(Qf, Kf, Vtf, E, lsum, ctxF, scale);
    colsum_kernel<<<dim3(7, 448), 256, 0, stream>>>(E, lsum, colsum, TP_H * TP_LQ);
    cast_div_bf16<<<(TP_LQ * TP_D / 4 + 255) / 256, 256, 0, stream>>>(ctxF, lsum, ctxB);

    // ---- O-projection split-K x2 -> pre1 (bias+residual in LN1)
    {
        GemmParams p{};
        p.A = ctxB; p.lda = TP_D;
        p.Bt = oWt; p.ldb = TP_D;
        p.M = TP_LQ; p.N = TP_D; p.K = 448; p.kc = 448;
        p.outF = pre1; p.ldc = TP_D;
        gemm_bf16<6><<<dim3(14, 13, 2), 256, 0, stream>>>(p);
    }
    layernorm_rows<<<TP_LQ, 256, 0, stream>>>(pre1, ob, mem, ln1g, ln1b, attn, attnB);

    // ---- MLP
    {
        GemmParams p{};
        p.A = attnB; p.lda = TP_D;
        p.Bt = mWt; p.ldb = TP_D;
        p.M = TP_LQ; p.N = TP_D4; p.K = TP_D;
        p.bias = mb; p.outB = hidden; p.ldc = TP_D4; p.relu = 1;
        gemm_bf16<4><<<dim3(56, 13, 1), 256, 0, stream>>>(p);
    }
    {   // MLP2 split-K x4 -> pre2 (bias+residual in LN2)
        GemmParams p{};
        p.A = hidden; p.lda = TP_D4;
        p.Bt = pWt; p.ldb = TP_D4;
        p.M = TP_LQ; p.N = TP_D; p.K = 896; p.kc = 896;
        p.outF = pre2; p.ldc = TP_D;
        gemm_bf16<6><<<dim3(14, 13, 4), 256, 0, stream>>>(p);
    }
    layernorm_rows<<<TP_LQ, 256, 0, stream>>>(pre2, pb, attn, ln2g, ln2b, out, nullptr);

    // ---- frame scores
    frame_scores_kernel<<<TP_F, 256, 0, stream>>>(colsum, out + (size_t)TP_LQ * TP_D);
}

// Round 12
// 461.838 us; speedup vs baseline: 1.4326x; 1.0794x over previous
//
#include <hip/hip_runtime.h>
#include <hip/hip_bf16.h>
#include <math.h>

#define TP_D   896
#define TP_H   8
#define TP_HD  112
#define TP_LQ  1568
#define TP_LK  6272
#define TP_D4  3584
#define TP_F   32
#define TP_P   196

typedef unsigned short u16;
typedef float f32x4 __attribute__((ext_vector_type(4)));
typedef __bf16 bf16x8 __attribute__((ext_vector_type(8)));

__device__ inline float bf2f(u16 u) {
    return __uint_as_float(((unsigned int)u) << 16);
}
__device__ inline u16 f2bf(float f) {
    unsigned int x = __float_as_uint(f);
    unsigned int lsb = (x >> 16) & 1u;
    x += 0x7fffu + lsb;
    return (u16)(x >> 16);
}
__device__ inline ushort4 pack4(float a, float b, float c, float d) {
    return make_ushort4(f2bf(a), f2bf(b), f2bf(c), f2bf(d));
}
// XOR-swizzled 128-col LDS tile index (16B-block swizzle) — attn only
__device__ inline int pidx(int row, int col) {
    return row * 128 + (col ^ ((row & 7) << 3));
}
// async global->LDS, 16B per lane, lands at ldsbase + lane*16
__device__ inline void gl_lds16(const u16* g, u16* l) {
    __builtin_amdgcn_global_load_lds(
        (const __attribute__((address_space(1))) unsigned int*)g,
        (__attribute__((address_space(3))) unsigned int*)l,
        16, 0, 0);
}

// ---------------------------------------------------------------- casts
// two arrays in one dispatch: [src0, n0) then [src1, n1)
__global__ void cast2_f32_bf16(const float* __restrict__ src0, u16* __restrict__ dst0, int n0,
                               const float* __restrict__ src1, u16* __restrict__ dst1, int n1) {
    int i = (blockIdx.x * blockDim.x + threadIdx.x) * 4;
    const float* s; u16* d; int n;
    if (i < n0) { s = src0; d = dst0; n = n0; }
    else        { i -= n0; s = src1; d = dst1; n = n1; if (i >= n) return; }
    float4 v = *(const float4*)(s + i);
    *(ushort4*)(d + i) = pack4(v.x, v.y, v.z, v.w);
}

// ctx fp32 (atomic-accumulated e*V) -> /l -> bf16
__global__ void cast_div_bf16(const float* __restrict__ src, const float* __restrict__ l,
                              u16* __restrict__ dst) {
    int i = (blockIdx.x * 256 + threadIdx.x) * 4;
    if (i >= TP_LQ * TP_D) return;
    int q = i / TP_D;
    int col = i - q * TP_D;
    int h = col / TP_HD;
    float inv = 1.f / l[h * TP_LQ + q];
    float4 v = *(const float4*)(src + i);
    *(ushort4*)(dst + i) = pack4(v.x * inv, v.y * inv, v.z * inv, v.w * inv);
}

// src fp32 [R][C] -> dst bf16 [C][R].  R,C multiples of 32. block (32,8)
__global__ void transpose_cast(const float* __restrict__ src, u16* __restrict__ dst, int R, int C) {
    __shared__ float t[32][33];
    int bx = blockIdx.x * 32;
    int by = blockIdx.y * 32;
    int tx = threadIdx.x, ty = threadIdx.y;
#pragma unroll
    for (int j = 0; j < 4; ++j)
        t[ty + j * 8][tx] = src[(size_t)(by + ty + j * 8) * C + bx + tx];
    __syncthreads();
#pragma unroll
    for (int j = 0; j < 4; ++j)
        dst[(size_t)(bx + ty + j * 8) * R + by + tx] = f2bf(t[tx][ty + j * 8]);
}

// four 896x896 transposes in one dispatch (z selects)
__global__ void transpose_cast4(const float* __restrict__ s0, u16* __restrict__ d0,
                                const float* __restrict__ s1, u16* __restrict__ d1,
                                const float* __restrict__ s2, u16* __restrict__ d2,
                                const float* __restrict__ s3, u16* __restrict__ d3) {
    __shared__ float t[32][33];
    const float* src; u16* dst;
    switch (blockIdx.z) {
        case 0: src = s0; dst = d0; break;
        case 1: src = s1; dst = d1; break;
        case 2: src = s2; dst = d2; break;
        default: src = s3; dst = d3; break;
    }
    int bx = blockIdx.x * 32;
    int by = blockIdx.y * 32;
    int tx = threadIdx.x, ty = threadIdx.y;
#pragma unroll
    for (int j = 0; j < 4; ++j)
        t[ty + j * 8][tx] = src[(size_t)(by + ty + j * 8) * TP_D + bx + tx];
    __syncthreads();
#pragma unroll
    for (int j = 0; j < 4; ++j)
        dst[(size_t)(bx + ty + j * 8) * TP_D + by + tx] = f2bf(t[tx][ty + j * 8]);
}

// ---------------------------------------------------------------- GEMM
// C[M,N] = A[M,K] @ Bt[N,K]^T, tile 128m x 64n, BK=32, global_load_lds staging.
// MODE 4: out bf16 = acc + bias[col] (relu optional)
// MODE 6: split-K: z = k-slice (chunk p.kc); atomicAdd fp32 into outF
struct GemmParams {
    const u16* A;  int lda;
    const u16* Bt; int ldb;
    int M, N, K;
    const float* bias;
    float* outF;
    u16* outB; int ldc;
    int relu;
    int kc;
};

template <int MODE>
__global__ __launch_bounds__(256, 4) void gemm_bf16(GemmParams p) {
    __shared__ u16 lsA[128 * 32];   // 8 KB
    __shared__ u16 lsB[64 * 32];    // 4 KB

    const int tid = threadIdx.x;
    const int z = blockIdx.z;
    const u16* A  = p.A;
    const u16* Bt = p.Bt;
    if (MODE == 6) {
        A  += (size_t)z * p.kc;
        Bt += (size_t)z * p.kc;
    }
    const int m0 = blockIdx.y * 128;
    const int n0 = blockIdx.x * 64;

    const int lane = tid & 63;
    const int w = tid >> 6;
    const int wm = (w >> 1) * 64, wn = (w & 1) * 32;
    const int c = lane & 15, q = lane >> 4;
    const int xq = (q ^ (c & 3)) << 3;     // swizzled chunk offset for reads

    f32x4 acc[4][2];
#pragma unroll
    for (int i = 0; i < 4; ++i) { acc[i][0] = 0.f; acc[i][1] = 0.f; }

    // staging geometry
    const int lrow = lane >> 2;                        // 0..15
    const int lchunk = (lane & 3) ^ (lrow & 3);        // logical chunk to fetch
    int ga_row0 = m0 + w * 32 + lrow;      if (ga_row0 >= p.M) ga_row0 = p.M - 1;
    int ga_row1 = m0 + w * 32 + 16 + lrow; if (ga_row1 >= p.M) ga_row1 = p.M - 1;
    int gb_row  = n0 + w * 16 + lrow;      if (gb_row  >= p.N) gb_row  = p.N - 1;
    const u16* gA0 = A  + (size_t)ga_row0 * p.lda + lchunk * 8;
    const u16* gA1 = A  + (size_t)ga_row1 * p.lda + lchunk * 8;
    const u16* gB  = Bt + (size_t)gb_row  * p.ldb + lchunk * 8;
    u16* lA0 = &lsA[(w * 32) * 32];
    u16* lA1 = &lsA[(w * 32 + 16) * 32];
    u16* lB  = &lsB[(w * 16) * 32];

    const int KT = p.K >> 5;
    for (int kt = 0; kt < KT; ++kt) {
        const int k0 = kt << 5;
        gl_lds16(gA0 + k0, lA0);
        gl_lds16(gA1 + k0, lA1);
        gl_lds16(gB + k0, lB);
        __syncthreads();   // drains DMA (vmcnt) + prior reads done

        bf16x8 af[4], bfv[2];
#pragma unroll
        for (int mi = 0; mi < 4; ++mi) {
            const int r = wm + mi * 16 + c;
            af[mi] = *(const bf16x8*)(&lsA[r * 32 + xq]);
        }
#pragma unroll
        for (int ni = 0; ni < 2; ++ni) {
            const int rb = wn + ni * 16 + c;
            bfv[ni] = *(const bf16x8*)(&lsB[rb * 32 + xq]);
        }
#pragma unroll
        for (int mi = 0; mi < 4; ++mi)
#pragma unroll
            for (int ni = 0; ni < 2; ++ni)
                acc[mi][ni] = __builtin_amdgcn_mfma_f32_16x16x32_bf16(af[mi], bfv[ni], acc[mi][ni], 0, 0, 0);
        __syncthreads();
    }

#pragma unroll
    for (int mi = 0; mi < 4; ++mi) {
#pragma unroll
        for (int r = 0; r < 4; ++r) {
            const int row = m0 + wm + mi * 16 + q * 4 + r;
            if (row >= p.M) continue;
#pragma unroll
            for (int ni = 0; ni < 2; ++ni) {
                const int col = n0 + wn + ni * 16 + c;
                float v = acc[mi][ni][r];
                if (MODE == 4) {
                    v += p.bias[col];
                    if (p.relu) v = v > 0.f ? v : 0.f;
                    p.outB[(size_t)row * p.ldc + col] = f2bf(v);
                } else if (MODE == 6) {
                    atomicAdd(&p.outF[(size_t)row * p.ldc + col], v);
                }
            }
        }
    }
}

// ---------------------------------------------------------------- QKV projection
// One dispatch, z in {0:K-proj, 1:V-proj (writes V^T), 2:Q-proj}.
__global__ __launch_bounds__(256, 4) void qkv_proj(
        const u16* __restrict__ imgB, const u16* __restrict__ memB,
        const u16* __restrict__ kWt, const u16* __restrict__ vWt, const u16* __restrict__ qWt,
        const float* __restrict__ kb, const float* __restrict__ vb, const float* __restrict__ qb,
        u16* __restrict__ Kf, u16* __restrict__ Vtf, u16* __restrict__ Qf) {
    __shared__ u16 lsA[128 * 32];
    __shared__ u16 lsB[64 * 32];

    const int z = blockIdx.z;
    const u16* A; const u16* Bt; const float* bias; int M;
    if (z == 0)      { A = imgB; Bt = kWt; bias = kb; M = TP_LK; }
    else if (z == 1) { A = imgB; Bt = vWt; bias = vb; M = TP_LK; }
    else             { A = memB; Bt = qWt; bias = qb; M = TP_LQ; }

    const int m0 = blockIdx.y * 128;
    if (m0 >= M) return;
    const int n0 = blockIdx.x * 64;

    const int tid = threadIdx.x;
    const int lane = tid & 63;
    const int w = tid >> 6;
    const int wm = (w >> 1) * 64, wn = (w & 1) * 32;
    const int c = lane & 15, q = lane >> 4;
    const int xq = (q ^ (c & 3)) << 3;

    f32x4 acc[4][2];
#pragma unroll
    for (int i = 0; i < 4; ++i) { acc[i][0] = 0.f; acc[i][1] = 0.f; }

    const int lrow = lane >> 2;
    const int lchunk = (lane & 3) ^ (lrow & 3);
    int ga_row0 = m0 + w * 32 + lrow;      if (ga_row0 >= M) ga_row0 = M - 1;
    int ga_row1 = m0 + w * 32 + 16 + lrow; if (ga_row1 >= M) ga_row1 = M - 1;
    const int gb_row = n0 + w * 16 + lrow;    // N = 896 exact
    const u16* gA0 = A  + (size_t)ga_row0 * TP_D + lchunk * 8;
    const u16* gA1 = A  + (size_t)ga_row1 * TP_D + lchunk * 8;
    const u16* gB  = Bt + (size_t)gb_row  * TP_D + lchunk * 8;
    u16* lA0 = &lsA[(w * 32) * 32];
    u16* lA1 = &lsA[(w * 32 + 16) * 32];
    u16* lB  = &lsB[(w * 16) * 32];

    for (int kt = 0; kt < 28; ++kt) {
        const int k0 = kt << 5;
        gl_lds16(gA0 + k0, lA0);
        gl_lds16(gA1 + k0, lA1);
        gl_lds16(gB + k0, lB);
        __syncthreads();

        bf16x8 af[4], bfv[2];
#pragma unroll
        for (int mi = 0; mi < 4; ++mi) {
            const int r = wm + mi * 16 + c;
            af[mi] = *(const bf16x8*)(&lsA[r * 32 + xq]);
        }
#pragma unroll
        for (int ni = 0; ni < 2; ++ni) {
            const int rb = wn + ni * 16 + c;
            bfv[ni] = *(const bf16x8*)(&lsB[rb * 32 + xq]);
        }
#pragma unroll
        for (int mi = 0; mi < 4; ++mi)
#pragma unroll
            for (int ni = 0; ni < 2; ++ni)
                acc[mi][ni] = __builtin_amdgcn_mfma_f32_16x16x32_bf16(af[mi], bfv[ni], acc[mi][ni], 0, 0, 0);
        __syncthreads();
    }

    if (z == 1) {
        // V^T epilogue: lane regs = 4 consecutive rows, contiguous along V^T inner dim
#pragma unroll
        for (int ni = 0; ni < 2; ++ni) {
            const int col = n0 + wn + ni * 16 + c;
            const float bv = bias[col];
#pragma unroll
            for (int mi = 0; mi < 4; ++mi) {
                const int mbase = m0 + wm + mi * 16 + q * 4;
                f32x4 a = acc[mi][ni];
                *(ushort4*)(Vtf + (size_t)col * TP_LK + mbase) =
                    pack4(a[0] + bv, a[1] + bv, a[2] + bv, a[3] + bv);
            }
        }
        return;
    }

    u16* outB = (z == 0) ? Kf : Qf;
#pragma unroll
    for (int mi = 0; mi < 4; ++mi) {
#pragma unroll
        for (int r = 0; r < 4; ++r) {
            const int row = m0 + wm + mi * 16 + q * 4 + r;
            if (row >= M) continue;
#pragma unroll
            for (int ni = 0; ni < 2; ++ni) {
                const int col = n0 + wn + ni * 16 + c;
                outB[(size_t)row * TP_D + col] = f2bf(acc[mi][ni][r] + bias[col]);
            }
        }
    }
}

// ---------------------------------------------------------------- fused attention
// R8 choreography; epilogue writes per-frame partial sums FQ instead of E.
// FQ[h*LQ+q][32]: F[h,q,f] = sum_{k in frame f} e[h,q,k].  l = sum_f F (finalize).
// grid (7 k-chunks, 13 q-tiles, 8 heads).
__global__ __launch_bounds__(256, 2) void attn_fused(
        const u16* __restrict__ Qf, const u16* __restrict__ Kf,
        const u16* __restrict__ Vtf, float* __restrict__ FQ,
        float* __restrict__ ctxF, float scale) {
    __shared__ u16 lsQ[128 * 128];   // swizzled, cols 112..127 zero
    __shared__ u16 lsB[128 * 40];    // K-tile or V-tile staging (32 cols)
    __shared__ u16 lsP[128 * 128];   // swizzled e tile

    const int ks  = blockIdx.x;
    const int m0  = blockIdx.y * 128;
    const int h   = blockIdx.z;
    const int tid = threadIdx.x;
    const int lane = tid & 63, w = tid >> 6;
    const int wm = (w >> 1) * 64, wn = (w & 1) * 64;
    const int c = lane & 15, q = lane >> 4;

    // ---- stage Q tile once (128 rows x 128 cols, 112 valid, zero-padded)
    {
        const int row = tid >> 1;
        const int half = (tid & 1) * 64;
        int qrow = m0 + row; if (qrow > TP_LQ - 1) qrow = TP_LQ - 1;
        const u16* src = Qf + (size_t)qrow * TP_D + h * TP_HD;
#pragma unroll
        for (int j = 0; j < 8; ++j) {
            int col = half + j * 8;
            uint4 v = make_uint4(0, 0, 0, 0);
            if (col + 8 <= TP_HD) v = *(const uint4*)(src + col);
            *(uint4*)(&lsQ[pidx(row, col)]) = v;
        }
    }

    const int r0 = tid >> 2;
    const int c8 = (tid & 3) * 8;
    const int keybase = ks * 896;

    f32x4 acc_pv[4][4];
#pragma unroll
    for (int i = 0; i < 4; ++i)
#pragma unroll
        for (int j = 0; j < 4; ++j) acc_pv[i][j] = 0.f;

    for (int kb = 0; kb < 7; ++kb) {
        const int kblk = keybase + kb * 128;
        f32x4 acc_s[4][4];
#pragma unroll
        for (int i = 0; i < 4; ++i)
#pragma unroll
            for (int j = 0; j < 4; ++j) acc_s[i][j] = 0.f;

        // ---- S phase: 4 kt over head dim (112, zero-padded to 128)
#pragma unroll
        for (int kt = 0; kt < 4; ++kt) {
            const int k0 = kt * 32;
            const bool valid = (k0 + c8 + 8) <= TP_HD;
            uint4 zv = make_uint4(0, 0, 0, 0);
            uint4 vb0 = valid ? *(const uint4*)(Kf + (size_t)(kblk + r0) * TP_D + h * TP_HD + k0 + c8) : zv;
            uint4 vb1 = valid ? *(const uint4*)(Kf + (size_t)(kblk + r0 + 64) * TP_D + h * TP_HD + k0 + c8) : zv;
            __syncthreads();   // protect lsB from previous consumer
            *(uint4*)(&lsB[r0 * 40 + c8])        = vb0;
            *(uint4*)(&lsB[(r0 + 64) * 40 + c8]) = vb1;
            __syncthreads();
            bf16x8 af[4], bfv[4];
#pragma unroll
            for (int mi = 0; mi < 4; ++mi)
                af[mi] = *(const bf16x8*)(&lsQ[pidx(wm + mi * 16 + c, k0 + q * 8)]);
#pragma unroll
            for (int ni = 0; ni < 4; ++ni)
                bfv[ni] = *(const bf16x8*)(&lsB[(wn + ni * 16 + c) * 40 + q * 8]);
#pragma unroll
            for (int mi = 0; mi < 4; ++mi)
#pragma unroll
                for (int ni = 0; ni < 4; ++ni)
                    acc_s[mi][ni] = __builtin_amdgcn_mfma_f32_16x16x32_bf16(bfv[ni], af[mi], acc_s[mi][ni], 0, 0, 0);
        }

        // ---- epilogue: e = exp(s*scale) -> lsP + per-frame partials (accA/accB)
        __syncthreads();   // previous PV reads of lsP complete
        const int fA = kblk / TP_P;               // frame of first key in block
        const int bpos = (fA + 1) * TP_P - kblk;  // local boundary, 1..196
        const int kq = wn + q * 4;                // local key base for this lane
#pragma unroll
        for (int mi = 0; mi < 4; ++mi) {
            const int prow = wm + mi * 16 + c;    // query row in tile
            float accA = 0.f, accB = 0.f;
#pragma unroll
            for (int ni = 0; ni < 4; ++ni) {
                f32x4 a = acc_s[mi][ni];
                float e0 = __expf(fminf(a[0] * scale, 30.f));
                float e1 = __expf(fminf(a[1] * scale, 30.f));
                float e2 = __expf(fminf(a[2] * scale, 30.f));
                float e3 = __expf(fminf(a[3] * scale, 30.f));
                const int kl = kq + ni * 16;
                accA += (kl + 0 < bpos) ? e0 : 0.f;  accB += (kl + 0 < bpos) ? 0.f : e0;
                accA += (kl + 1 < bpos) ? e1 : 0.f;  accB += (kl + 1 < bpos) ? 0.f : e1;
                accA += (kl + 2 < bpos) ? e2 : 0.f;  accB += (kl + 2 < bpos) ? 0.f : e2;
                accA += (kl + 3 < bpos) ? e3 : 0.f;  accB += (kl + 3 < bpos) ? 0.f : e3;
                *(ushort4*)(&lsP[pidx(prow, kl)]) = pack4(e0, e1, e2, e3);
            }
            accA += __shfl_xor(accA, 16, 64); accA += __shfl_xor(accA, 32, 64);
            accB += __shfl_xor(accB, 16, 64); accB += __shfl_xor(accB, 32, 64);
            const int qr = m0 + prow;
            if (q == 0 && qr < TP_LQ) {
                float* fq = &FQ[((size_t)h * TP_LQ + qr) * TP_F];
                atomicAdd(fq + fA, accA);
                if (bpos < 128) atomicAdd(fq + fA + 1, accB);
            }
        }

        // ---- PV phase: 4 kt over the 128 keys of this block
#pragma unroll
        for (int kt = 0; kt < 4; ++kt) {
            const int kk = kblk + kt * 32 + c8;
            int d0 = r0;                               // < 112 always
            int d1 = r0 + 64; if (d1 > TP_HD - 1) d1 = TP_HD - 1;
            uint4 vb0 = *(const uint4*)(Vtf + ((size_t)h * TP_HD + d0) * TP_LK + kk);
            uint4 vb1 = *(const uint4*)(Vtf + ((size_t)h * TP_HD + d1) * TP_LK + kk);
            __syncthreads();   // lsB reuse; first iter: lsP writes visible
            *(uint4*)(&lsB[r0 * 40 + c8])        = vb0;
            *(uint4*)(&lsB[(r0 + 64) * 40 + c8]) = vb1;
            __syncthreads();
            bf16x8 ap[4], bv[4];
#pragma unroll
            for (int mi = 0; mi < 4; ++mi)
                ap[mi] = *(const bf16x8*)(&lsP[pidx(wm + mi * 16 + c, kt * 32 + q * 8)]);
#pragma unroll
            for (int ni = 0; ni < 4; ++ni)
                bv[ni] = *(const bf16x8*)(&lsB[(wn + ni * 16 + c) * 40 + q * 8]);
#pragma unroll
            for (int mi = 0; mi < 4; ++mi)
#pragma unroll
                for (int ni = 0; ni < 4; ++ni)
                    acc_pv[mi][ni] = __builtin_amdgcn_mfma_f32_16x16x32_bf16(ap[mi], bv[ni], acc_pv[mi][ni], 0, 0, 0);
        }
    }

    // ---- ctx atomics (normal C/D layout: col=d, rows q*4+r)
#pragma unroll
    for (int mi = 0; mi < 4; ++mi) {
#pragma unroll
        for (int r = 0; r < 4; ++r) {
            const int qr = m0 + wm + mi * 16 + q * 4 + r;
            if (qr >= TP_LQ) continue;
#pragma unroll
            for (int ni = 0; ni < 4; ++ni) {
                const int d = wn + ni * 16 + c;
                if (d < TP_HD)
                    atomicAdd(&ctxF[(size_t)qr * TP_D + h * TP_HD + d], acc_pv[mi][ni][r]);
            }
        }
    }
}

// ---------------------------------------------------------------- frame finalize
// One thread per (h,query) row of FQ: l = sum_f F; lsum = l; block-reduce
// F/l into the 32 frame scores (pre-scaled by 1/196) via atomics into out.
__global__ __launch_bounds__(256) void frame_finalize(
        const float* __restrict__ FQ, float* __restrict__ lsum,
        float* __restrict__ frame_out) {
    __shared__ float red[256 * 33];
    const int tid = threadIdx.x;
    const int row = blockIdx.x * 256 + tid;   // 0..12543 exact (49*256)
    float v[32];
    const float4* src = (const float4*)(FQ + (size_t)row * TP_F);
    float l = 0.f;
#pragma unroll
    for (int i = 0; i < 8; ++i) {
        float4 t = src[i];
        v[4 * i + 0] = t.x; v[4 * i + 1] = t.y;
        v[4 * i + 2] = t.z; v[4 * i + 3] = t.w;
        l += (t.x + t.y) + (t.z + t.w);
    }
    lsum[row] = l;
    const float inv = 1.f / l;
#pragma unroll
    for (int f = 0; f < 32; ++f) red[tid * 33 + f] = v[f] * inv;
    __syncthreads();
    if (tid < 32) {
        float s = 0.f;
        for (int t = 0; t < 256; ++t) s += red[t * 33 + tid];
        atomicAdd(&frame_out[tid], s * (1.f / TP_P));
    }
}

// ---------------------------------------------------------------- layernorm
// t = x + bias + res; out = LN(t)*g + b
__global__ __launch_bounds__(256) void layernorm_rows(const float* __restrict__ x,
        const float* __restrict__ bias, const float* __restrict__ res,
        const float* __restrict__ g, const float* __restrict__ b,
        float* __restrict__ outF, u16* __restrict__ outB) {
    const int tid = threadIdx.x;
    const float* xr = x + (size_t)blockIdx.x * TP_D;
    const float* rr = res + (size_t)blockIdx.x * TP_D;
    float v[4];
#pragma unroll
    for (int i = 0; i < 4; ++i) {
        int idx = tid + i * 256;
        v[i] = (idx < TP_D) ? (xr[idx] + bias[idx] + rr[idx]) : 0.f;
    }
    float s = v[0] + v[1] + v[2] + v[3];
    __shared__ float red[4];
#pragma unroll
    for (int o = 32; o > 0; o >>= 1) s += __shfl_xor(s, o, 64);
    if ((tid & 63) == 0) red[tid >> 6] = s;
    __syncthreads();
    const float mu = (red[0] + red[1] + red[2] + red[3]) * (1.f / TP_D);
    __syncthreads();
    float ss = 0.f;
#pragma unroll
    for (int i = 0; i < 4; ++i) {
        int idx = tid + i * 256;
        if (idx < TP_D) { float d = v[i] - mu; ss += d * d; }
    }
#pragma unroll
    for (int o = 32; o > 0; o >>= 1) ss += __shfl_xor(ss, o, 64);
    if ((tid & 63) == 0) red[tid >> 6] = ss;
    __syncthreads();
    const float var = (red[0] + red[1] + red[2] + red[3]) * (1.f / TP_D);
    const float rsq = rsqrtf(var + 1e-12f);
    float* of = outF + (size_t)blockIdx.x * TP_D;
    u16* obp = outB ? outB + (size_t)blockIdx.x * TP_D : nullptr;
#pragma unroll
    for (int i = 0; i < 4; ++i) {
        int idx = tid + i * 256;
        if (idx < TP_D) {
            float y = (v[i] - mu) * rsq * g[idx] + b[idx];
            of[idx] = y;
            if (obp) obp[idx] = f2bf(y);
        }
    }
}

// ---------------------------------------------------------------- launch
extern "C" void kernel_launch(void* const* d_in, const int* in_sizes, int n_in,
                              void* d_out, int out_size, void* d_ws, size_t ws_size,
                              hipStream_t stream) {
    const float* img  = (const float*)d_in[0];
    const float* mem  = (const float*)d_in[1];
    const float* qW   = (const float*)d_in[2];
    const float* qb   = (const float*)d_in[3];
    const float* kW   = (const float*)d_in[4];
    const float* kb   = (const float*)d_in[5];
    const float* vW   = (const float*)d_in[6];
    const float* vb   = (const float*)d_in[7];
    const float* oW   = (const float*)d_in[8];
    const float* ob   = (const float*)d_in[9];
    const float* ln1g = (const float*)d_in[10];
    const float* ln1b = (const float*)d_in[11];
    const float* mW   = (const float*)d_in[12];
    const float* mb   = (const float*)d_in[13];
    const float* pW   = (const float*)d_in[14];
    const float* pb   = (const float*)d_in[15];
    const float* ln2g = (const float*)d_in[16];
    const float* ln2b = (const float*)d_in[17];
    float* out = (float*)d_out;

    char* base = (char*)d_ws;
    size_t off = 0;
    auto take = [&](size_t nbytes) -> void* {
        void* p = base + off;
        off += (nbytes + 255) & ~(size_t)255;
        return p;
    };

    u16* imgB  = (u16*)take((size_t)TP_LK * TP_D * 2);
    u16* memB  = (u16*)take((size_t)TP_LQ * TP_D * 2);
    u16* qWt   = (u16*)take((size_t)TP_D * TP_D * 2);
    u16* kWt   = (u16*)take((size_t)TP_D * TP_D * 2);
    u16* vWt   = (u16*)take((size_t)TP_D * TP_D * 2);
    u16* oWt   = (u16*)take((size_t)TP_D * TP_D * 2);
    u16* mWt   = (u16*)take((size_t)TP_D * TP_D4 * 2);
    u16* pWt   = (u16*)take((size_t)TP_D * TP_D4 * 2);
    u16* Qf    = (u16*)take((size_t)TP_LQ * TP_D * 2);
    u16* Kf    = (u16*)take((size_t)TP_LK * TP_D * 2);
    u16* Vtf   = (u16*)take((size_t)TP_LK * TP_D * 2);
    u16* ctxB  = (u16*)take((size_t)TP_LQ * TP_D * 2);
    float* attn  = (float*)take((size_t)TP_LQ * TP_D * 4);
    u16* attnB = (u16*)take((size_t)TP_LQ * TP_D * 2);
    u16* hidden= (u16*)take((size_t)TP_LQ * TP_D4 * 2);
    float* lsum  = (float*)take((size_t)TP_H * TP_LQ * 4);
    // ---- contiguous zero region (single memset) ----
    float* ctxF  = (float*)take((size_t)TP_LQ * TP_D * 4);
    float* pre1  = (float*)take((size_t)TP_LQ * TP_D * 4);
    float* pre2  = (float*)take((size_t)TP_LQ * TP_D * 4);
    float* FQ    = (float*)take((size_t)TP_H * TP_LQ * TP_F * 4);
    size_t zlen = (char*)(FQ + (size_t)TP_H * TP_LQ * TP_F) - (char*)ctxF;

    // ---- casts / transposes / zero-init
    {
        int n0 = TP_LK * TP_D, n1 = TP_LQ * TP_D;
        cast2_f32_bf16<<<((n0 + n1) / 4 + 255) / 256, 256, 0, stream>>>(img, imgB, n0, mem, memB, n1);
    }
    transpose_cast4<<<dim3(28, 28, 4), dim3(32, 8), 0, stream>>>(qW, qWt, kW, kWt, vW, vWt, oW, oWt);
    transpose_cast<<<dim3(TP_D4 / 32, TP_D / 32), dim3(32, 8), 0, stream>>>(mW, mWt, TP_D, TP_D4);
    transpose_cast<<<dim3(TP_D / 32, TP_D4 / 32), dim3(32, 8), 0, stream>>>(pW, pWt, TP_D4, TP_D);
    hipMemsetAsync(ctxF, 0, zlen, stream);
    hipMemsetAsync(out + (size_t)TP_LQ * TP_D, 0, TP_F * 4, stream);

    // ---- QKV projections in one dispatch (z: 0=K, 1=V^T, 2=Q)
    qkv_proj<<<dim3(14, 49, 3), 256, 0, stream>>>(imgB, memB, kWt, vWt, qWt,
                                                  kb, vb, qb, Kf, Vtf, Qf);

    // ---- fused attention (S + exp + FQ + PV), finalize (lsum + frame scores)
    const float scale = 0.09449111825230679f;  // 1/sqrt(112)
    attn_fused<<<dim3(7, 13, TP_H), 256, 0, stream>>>(Qf, Kf, Vtf, FQ, ctxF, scale);
    frame_finalize<<<49, 256, 0, stream>>>(FQ, lsum, out + (size_t)TP_LQ * TP_D);
    cast_div_bf16<<<(TP_LQ * TP_D / 4 + 255) / 256, 256, 0, stream>>>(ctxF, lsum, ctxB);

    // ---- O-projection split-K x2 -> pre1 (bias+residual in LN1)
    {
        GemmParams p{};
        p.A = ctxB; p.lda = TP_D;
        p.Bt = oWt; p.ldb = TP_D;
        p.M = TP_LQ; p.N = TP_D; p.K = 448; p.kc = 448;
        p.outF = pre1; p.ldc = TP_D;
        gemm_bf16<6><<<dim3(14, 13, 2), 256, 0, stream>>>(p);
    }
    layernorm_rows<<<TP_LQ, 256, 0, stream>>>(pre1, ob, mem, ln1g, ln1b, attn, attnB);

    // ---- MLP
    {
        GemmParams p{};
        p.A = attnB; p.lda = TP_D;
        p.Bt = mWt; p.ldb = TP_D;
        p.M = TP_LQ; p.N = TP_D4; p.K = TP_D;
        p.bias = mb; p.outB = hidden; p.ldc = TP_D4; p.relu = 1;
        gemm_bf16<4><<<dim3(56, 13, 1), 256, 0, stream>>>(p);
    }
    {   // MLP2 split-K x4 -> pre2 (bias+residual in LN2)
        GemmParams p{};
        p.A = hidden; p.lda = TP_D4;
        p.Bt = pWt; p.ldb = TP_D4;
        p.M = TP_LQ; p.N = TP_D; p.K = 896; p.kc = 896;
        p.outF = pre2; p.ldc = TP_D;
        gemm_bf16<6><<<dim3(14, 13, 4), 256, 0, stream>>>(p);
    }
    layernorm_rows<<<TP_LQ, 256, 0, stream>>>(pre2, pb, attn, ln2g, ln2b, out, nullptr);
}

// Round 13
// 451.409 us; speedup vs baseline: 1.4657x; 1.0231x over previous
//
#include <hip/hip_runtime.h>
#include <hip/hip_bf16.h>
#include <math.h>

#define TP_D   896
#define TP_H   8
#define TP_HD  112
#define TP_LQ  1568
#define TP_LK  6272
#define TP_D4  3584
#define TP_F   32
#define TP_P   196

typedef unsigned short u16;
typedef float f32x4 __attribute__((ext_vector_type(4)));
typedef __bf16 bf16x8 __attribute__((ext_vector_type(8)));

__device__ inline float bf2f(u16 u) {
    return __uint_as_float(((unsigned int)u) << 16);
}
__device__ inline u16 f2bf(float f) {
    unsigned int x = __float_as_uint(f);
    unsigned int lsb = (x >> 16) & 1u;
    x += 0x7fffu + lsb;
    return (u16)(x >> 16);
}
__device__ inline ushort4 pack4(float a, float b, float c, float d) {
    return make_ushort4(f2bf(a), f2bf(b), f2bf(c), f2bf(d));
}
// truncation pack: bf16(a) in low half, bf16(b) in high half (2 VALU ops)
__device__ inline unsigned packt2(float a, float b) {
    return (__float_as_uint(a) >> 16) | (__float_as_uint(b) & 0xffff0000u);
}
// XOR-swizzled 128-col LDS tile index (16B-block swizzle) — attn only
__device__ inline int pidx(int row, int col) {
    return row * 128 + (col ^ ((row & 7) << 3));
}
// async global->LDS, 16B per lane, lands at ldsbase + lane*16
__device__ inline void gl_lds16(const u16* g, u16* l) {
    __builtin_amdgcn_global_load_lds(
        (const __attribute__((address_space(1))) unsigned int*)g,
        (__attribute__((address_space(3))) unsigned int*)l,
        16, 0, 0);
}

// ---------------------------------------------------------------- casts
// two arrays in one dispatch: [src0, n0) then [src1, n1)
__global__ void cast2_f32_bf16(const float* __restrict__ src0, u16* __restrict__ dst0, int n0,
                               const float* __restrict__ src1, u16* __restrict__ dst1, int n1) {
    int i = (blockIdx.x * blockDim.x + threadIdx.x) * 4;
    const float* s; u16* d; int n;
    if (i < n0) { s = src0; d = dst0; n = n0; }
    else        { i -= n0; s = src1; d = dst1; n = n1; if (i >= n) return; }
    float4 v = *(const float4*)(s + i);
    *(ushort4*)(d + i) = pack4(v.x, v.y, v.z, v.w);
}

// ctx fp32 (atomic-accumulated e*V) -> /l -> bf16
__global__ void cast_div_bf16(const float* __restrict__ src, const float* __restrict__ l,
                              u16* __restrict__ dst) {
    int i = (blockIdx.x * 256 + threadIdx.x) * 4;
    if (i >= TP_LQ * TP_D) return;
    int q = i / TP_D;
    int col = i - q * TP_D;
    int h = col / TP_HD;
    float inv = 1.f / l[h * TP_LQ + q];
    float4 v = *(const float4*)(src + i);
    *(ushort4*)(dst + i) = pack4(v.x * inv, v.y * inv, v.z * inv, v.w * inv);
}

// src fp32 [R][C] -> dst bf16 [C][R].  R,C multiples of 32. block (32,8)
__global__ void transpose_cast(const float* __restrict__ src, u16* __restrict__ dst, int R, int C) {
    __shared__ float t[32][33];
    int bx = blockIdx.x * 32;
    int by = blockIdx.y * 32;
    int tx = threadIdx.x, ty = threadIdx.y;
#pragma unroll
    for (int j = 0; j < 4; ++j)
        t[ty + j * 8][tx] = src[(size_t)(by + ty + j * 8) * C + bx + tx];
    __syncthreads();
#pragma unroll
    for (int j = 0; j < 4; ++j)
        dst[(size_t)(bx + ty + j * 8) * R + by + tx] = f2bf(t[tx][ty + j * 8]);
}

// four 896x896 transposes in one dispatch (z selects)
__global__ void transpose_cast4(const float* __restrict__ s0, u16* __restrict__ d0,
                                const float* __restrict__ s1, u16* __restrict__ d1,
                                const float* __restrict__ s2, u16* __restrict__ d2,
                                const float* __restrict__ s3, u16* __restrict__ d3) {
    __shared__ float t[32][33];
    const float* src; u16* dst;
    switch (blockIdx.z) {
        case 0: src = s0; dst = d0; break;
        case 1: src = s1; dst = d1; break;
        case 2: src = s2; dst = d2; break;
        default: src = s3; dst = d3; break;
    }
    int bx = blockIdx.x * 32;
    int by = blockIdx.y * 32;
    int tx = threadIdx.x, ty = threadIdx.y;
#pragma unroll
    for (int j = 0; j < 4; ++j)
        t[ty + j * 8][tx] = src[(size_t)(by + ty + j * 8) * TP_D + bx + tx];
    __syncthreads();
#pragma unroll
    for (int j = 0; j < 4; ++j)
        dst[(size_t)(bx + ty + j * 8) * TP_D + by + tx] = f2bf(t[tx][ty + j * 8]);
}

// ---------------------------------------------------------------- GEMM
// C[M,N] = A[M,K] @ Bt[N,K]^T, tile 128m x 64n, BK=32, global_load_lds staging.
// MODE 4: out bf16 = acc + bias[col] (relu optional)
// MODE 6: split-K: z = k-slice (chunk p.kc); atomicAdd fp32 into outF
struct GemmParams {
    const u16* A;  int lda;
    const u16* Bt; int ldb;
    int M, N, K;
    const float* bias;
    float* outF;
    u16* outB; int ldc;
    int relu;
    int kc;
};

template <int MODE>
__global__ __launch_bounds__(256, 4) void gemm_bf16(GemmParams p) {
    __shared__ u16 lsA[128 * 32];   // 8 KB
    __shared__ u16 lsB[64 * 32];    // 4 KB

    const int tid = threadIdx.x;
    const int z = blockIdx.z;
    const u16* A  = p.A;
    const u16* Bt = p.Bt;
    if (MODE == 6) {
        A  += (size_t)z * p.kc;
        Bt += (size_t)z * p.kc;
    }
    const int m0 = blockIdx.y * 128;
    const int n0 = blockIdx.x * 64;

    const int lane = tid & 63;
    const int w = tid >> 6;
    const int wm = (w >> 1) * 64, wn = (w & 1) * 32;
    const int c = lane & 15, q = lane >> 4;
    const int xq = (q ^ (c & 3)) << 3;     // swizzled chunk offset for reads

    f32x4 acc[4][2];
#pragma unroll
    for (int i = 0; i < 4; ++i) { acc[i][0] = 0.f; acc[i][1] = 0.f; }

    // staging geometry
    const int lrow = lane >> 2;                        // 0..15
    const int lchunk = (lane & 3) ^ (lrow & 3);        // logical chunk to fetch
    int ga_row0 = m0 + w * 32 + lrow;      if (ga_row0 >= p.M) ga_row0 = p.M - 1;
    int ga_row1 = m0 + w * 32 + 16 + lrow; if (ga_row1 >= p.M) ga_row1 = p.M - 1;
    int gb_row  = n0 + w * 16 + lrow;      if (gb_row  >= p.N) gb_row  = p.N - 1;
    const u16* gA0 = A  + (size_t)ga_row0 * p.lda + lchunk * 8;
    const u16* gA1 = A  + (size_t)ga_row1 * p.lda + lchunk * 8;
    const u16* gB  = Bt + (size_t)gb_row  * p.ldb + lchunk * 8;
    u16* lA0 = &lsA[(w * 32) * 32];
    u16* lA1 = &lsA[(w * 32 + 16) * 32];
    u16* lB  = &lsB[(w * 16) * 32];

    const int KT = p.K >> 5;
    for (int kt = 0; kt < KT; ++kt) {
        const int k0 = kt << 5;
        gl_lds16(gA0 + k0, lA0);
        gl_lds16(gA1 + k0, lA1);
        gl_lds16(gB + k0, lB);
        __syncthreads();   // drains DMA (vmcnt) + prior reads done

        bf16x8 af[4], bfv[2];
#pragma unroll
        for (int mi = 0; mi < 4; ++mi) {
            const int r = wm + mi * 16 + c;
            af[mi] = *(const bf16x8*)(&lsA[r * 32 + xq]);
        }
#pragma unroll
        for (int ni = 0; ni < 2; ++ni) {
            const int rb = wn + ni * 16 + c;
            bfv[ni] = *(const bf16x8*)(&lsB[rb * 32 + xq]);
        }
#pragma unroll
        for (int mi = 0; mi < 4; ++mi)
#pragma unroll
            for (int ni = 0; ni < 2; ++ni)
                acc[mi][ni] = __builtin_amdgcn_mfma_f32_16x16x32_bf16(af[mi], bfv[ni], acc[mi][ni], 0, 0, 0);
        __syncthreads();
    }

#pragma unroll
    for (int mi = 0; mi < 4; ++mi) {
#pragma unroll
        for (int r = 0; r < 4; ++r) {
            const int row = m0 + wm + mi * 16 + q * 4 + r;
            if (row >= p.M) continue;
#pragma unroll
            for (int ni = 0; ni < 2; ++ni) {
                const int col = n0 + wn + ni * 16 + c;
                float v = acc[mi][ni][r];
                if (MODE == 4) {
                    v += p.bias[col];
                    if (p.relu) v = v > 0.f ? v : 0.f;
                    p.outB[(size_t)row * p.ldc + col] = f2bf(v);
                } else if (MODE == 6) {
                    atomicAdd(&p.outF[(size_t)row * p.ldc + col], v);
                }
            }
        }
    }
}

// ---------------------------------------------------------------- QKV projection
// One dispatch, z in {0:K-proj, 1:V-proj (writes V^T), 2:Q-proj}.
__global__ __launch_bounds__(256, 4) void qkv_proj(
        const u16* __restrict__ imgB, const u16* __restrict__ memB,
        const u16* __restrict__ kWt, const u16* __restrict__ vWt, const u16* __restrict__ qWt,
        const float* __restrict__ kb, const float* __restrict__ vb, const float* __restrict__ qb,
        u16* __restrict__ Kf, u16* __restrict__ Vtf, u16* __restrict__ Qf) {
    __shared__ u16 lsA[128 * 32];
    __shared__ u16 lsB[64 * 32];

    const int z = blockIdx.z;
    const u16* A; const u16* Bt; const float* bias; int M;
    if (z == 0)      { A = imgB; Bt = kWt; bias = kb; M = TP_LK; }
    else if (z == 1) { A = imgB; Bt = vWt; bias = vb; M = TP_LK; }
    else             { A = memB; Bt = qWt; bias = qb; M = TP_LQ; }

    const int m0 = blockIdx.y * 128;
    if (m0 >= M) return;
    const int n0 = blockIdx.x * 64;

    const int tid = threadIdx.x;
    const int lane = tid & 63;
    const int w = tid >> 6;
    const int wm = (w >> 1) * 64, wn = (w & 1) * 32;
    const int c = lane & 15, q = lane >> 4;
    const int xq = (q ^ (c & 3)) << 3;

    f32x4 acc[4][2];
#pragma unroll
    for (int i = 0; i < 4; ++i) { acc[i][0] = 0.f; acc[i][1] = 0.f; }

    const int lrow = lane >> 2;
    const int lchunk = (lane & 3) ^ (lrow & 3);
    int ga_row0 = m0 + w * 32 + lrow;      if (ga_row0 >= M) ga_row0 = M - 1;
    int ga_row1 = m0 + w * 32 + 16 + lrow; if (ga_row1 >= M) ga_row1 = M - 1;
    const int gb_row = n0 + w * 16 + lrow;    // N = 896 exact
    const u16* gA0 = A  + (size_t)ga_row0 * TP_D + lchunk * 8;
    const u16* gA1 = A  + (size_t)ga_row1 * TP_D + lchunk * 8;
    const u16* gB  = Bt + (size_t)gb_row  * TP_D + lchunk * 8;
    u16* lA0 = &lsA[(w * 32) * 32];
    u16* lA1 = &lsA[(w * 32 + 16) * 32];
    u16* lB  = &lsB[(w * 16) * 32];

    for (int kt = 0; kt < 28; ++kt) {
        const int k0 = kt << 5;
        gl_lds16(gA0 + k0, lA0);
        gl_lds16(gA1 + k0, lA1);
        gl_lds16(gB + k0, lB);
        __syncthreads();

        bf16x8 af[4], bfv[2];
#pragma unroll
        for (int mi = 0; mi < 4; ++mi) {
            const int r = wm + mi * 16 + c;
            af[mi] = *(const bf16x8*)(&lsA[r * 32 + xq]);
        }
#pragma unroll
        for (int ni = 0; ni < 2; ++ni) {
            const int rb = wn + ni * 16 + c;
            bfv[ni] = *(const bf16x8*)(&lsB[rb * 32 + xq]);
        }
#pragma unroll
        for (int mi = 0; mi < 4; ++mi)
#pragma unroll
            for (int ni = 0; ni < 2; ++ni)
                acc[mi][ni] = __builtin_amdgcn_mfma_f32_16x16x32_bf16(af[mi], bfv[ni], acc[mi][ni], 0, 0, 0);
        __syncthreads();
    }

    if (z == 1) {
        // V^T epilogue: lane regs = 4 consecutive rows, contiguous along V^T inner dim
#pragma unroll
        for (int ni = 0; ni < 2; ++ni) {
            const int col = n0 + wn + ni * 16 + c;
            const float bv = bias[col];
#pragma unroll
            for (int mi = 0; mi < 4; ++mi) {
                const int mbase = m0 + wm + mi * 16 + q * 4;
                f32x4 a = acc[mi][ni];
                *(ushort4*)(Vtf + (size_t)col * TP_LK + mbase) =
                    pack4(a[0] + bv, a[1] + bv, a[2] + bv, a[3] + bv);
            }
        }
        return;
    }

    u16* outB = (z == 0) ? Kf : Qf;
#pragma unroll
    for (int mi = 0; mi < 4; ++mi) {
#pragma unroll
        for (int r = 0; r < 4; ++r) {
            const int row = m0 + wm + mi * 16 + q * 4 + r;
            if (row >= M) continue;
#pragma unroll
            for (int ni = 0; ni < 2; ++ni) {
                const int col = n0 + wn + ni * 16 + c;
                outB[(size_t)row * TP_D + col] = f2bf(acc[mi][ni][r] + bias[col]);
            }
        }
    }
}

// ---------------------------------------------------------------- fused attention
// R8 choreography; epilogue writes per-frame partial sums FQ (no E matrix).
// lsP packed by truncation (2 ops/pair); accB derived as tot-accA.
// grid (7 k-chunks, 13 q-tiles, 8 heads).
__global__ __launch_bounds__(256, 2) void attn_fused(
        const u16* __restrict__ Qf, const u16* __restrict__ Kf,
        const u16* __restrict__ Vtf, float* __restrict__ FQ,
        float* __restrict__ ctxF, float scale) {
    __shared__ u16 lsQ[128 * 128];   // swizzled, cols 112..127 zero
    __shared__ u16 lsB[128 * 40];    // K-tile or V-tile staging (32 cols)
    __shared__ u16 lsP[128 * 128];   // swizzled e tile

    const int ks  = blockIdx.x;
    const int m0  = blockIdx.y * 128;
    const int h   = blockIdx.z;
    const int tid = threadIdx.x;
    const int lane = tid & 63, w = tid >> 6;
    const int wm = (w >> 1) * 64, wn = (w & 1) * 64;
    const int c = lane & 15, q = lane >> 4;

    // ---- stage Q tile once (128 rows x 128 cols, 112 valid, zero-padded)
    {
        const int row = tid >> 1;
        const int half = (tid & 1) * 64;
        int qrow = m0 + row; if (qrow > TP_LQ - 1) qrow = TP_LQ - 1;
        const u16* src = Qf + (size_t)qrow * TP_D + h * TP_HD;
#pragma unroll
        for (int j = 0; j < 8; ++j) {
            int col = half + j * 8;
            uint4 v = make_uint4(0, 0, 0, 0);
            if (col + 8 <= TP_HD) v = *(const uint4*)(src + col);
            *(uint4*)(&lsQ[pidx(row, col)]) = v;
        }
    }

    const int r0 = tid >> 2;
    const int c8 = (tid & 3) * 8;
    const int keybase = ks * 896;

    f32x4 acc_pv[4][4];
#pragma unroll
    for (int i = 0; i < 4; ++i)
#pragma unroll
        for (int j = 0; j < 4; ++j) acc_pv[i][j] = 0.f;

    for (int kb = 0; kb < 7; ++kb) {
        const int kblk = keybase + kb * 128;
        f32x4 acc_s[4][4];
#pragma unroll
        for (int i = 0; i < 4; ++i)
#pragma unroll
            for (int j = 0; j < 4; ++j) acc_s[i][j] = 0.f;

        // ---- S phase: 4 kt over head dim (112, zero-padded to 128)
#pragma unroll
        for (int kt = 0; kt < 4; ++kt) {
            const int k0 = kt * 32;
            const bool valid = (k0 + c8 + 8) <= TP_HD;
            uint4 zv = make_uint4(0, 0, 0, 0);
            uint4 vb0 = valid ? *(const uint4*)(Kf + (size_t)(kblk + r0) * TP_D + h * TP_HD + k0 + c8) : zv;
            uint4 vb1 = valid ? *(const uint4*)(Kf + (size_t)(kblk + r0 + 64) * TP_D + h * TP_HD + k0 + c8) : zv;
            __syncthreads();   // protect lsB from previous consumer
            *(uint4*)(&lsB[r0 * 40 + c8])        = vb0;
            *(uint4*)(&lsB[(r0 + 64) * 40 + c8]) = vb1;
            __syncthreads();
            bf16x8 af[4], bfv[4];
#pragma unroll
            for (int mi = 0; mi < 4; ++mi)
                af[mi] = *(const bf16x8*)(&lsQ[pidx(wm + mi * 16 + c, k0 + q * 8)]);
#pragma unroll
            for (int ni = 0; ni < 4; ++ni)
                bfv[ni] = *(const bf16x8*)(&lsB[(wn + ni * 16 + c) * 40 + q * 8]);
#pragma unroll
            for (int mi = 0; mi < 4; ++mi)
#pragma unroll
                for (int ni = 0; ni < 4; ++ni)
                    acc_s[mi][ni] = __builtin_amdgcn_mfma_f32_16x16x32_bf16(bfv[ni], af[mi], acc_s[mi][ni], 0, 0, 0);
        }

        // ---- epilogue: e = exp(s*scale) -> lsP (truncated) + frame partials
        __syncthreads();   // previous PV reads of lsP complete
        const int fA = kblk / TP_P;               // frame of first key in block
        const int bpos = (fA + 1) * TP_P - kblk;  // local boundary, 1..196
        const int kq = wn + q * 4;                // local key base for this lane
#pragma unroll
        for (int mi = 0; mi < 4; ++mi) {
            const int prow = wm + mi * 16 + c;    // query row in tile
            float tot = 0.f, accA = 0.f;
#pragma unroll
            for (int ni = 0; ni < 4; ++ni) {
                f32x4 a = acc_s[mi][ni];
                float e0 = __expf(a[0] * scale);
                float e1 = __expf(a[1] * scale);
                float e2 = __expf(a[2] * scale);
                float e3 = __expf(a[3] * scale);
                tot += (e0 + e1) + (e2 + e3);
                const int kl = kq + ni * 16;
                accA += (kl + 0 < bpos) ? e0 : 0.f;
                accA += (kl + 1 < bpos) ? e1 : 0.f;
                accA += (kl + 2 < bpos) ? e2 : 0.f;
                accA += (kl + 3 < bpos) ? e3 : 0.f;
                *(uint2*)(&lsP[pidx(prow, kl)]) = make_uint2(packt2(e0, e1), packt2(e2, e3));
            }
            accA += __shfl_xor(accA, 16, 64); accA += __shfl_xor(accA, 32, 64);
            tot  += __shfl_xor(tot, 16, 64);  tot  += __shfl_xor(tot, 32, 64);
            const int qr = m0 + prow;
            if (q == 0 && qr < TP_LQ) {
                float* fq = &FQ[((size_t)h * TP_LQ + qr) * TP_F];
                atomicAdd(fq + fA, accA);
                if (bpos < 128) atomicAdd(fq + fA + 1, tot - accA);
            }
        }

        // ---- PV phase: 4 kt over the 128 keys of this block
#pragma unroll
        for (int kt = 0; kt < 4; ++kt) {
            const int kk = kblk + kt * 32 + c8;
            int d0 = r0;                               // < 112 always
            int d1 = r0 + 64; if (d1 > TP_HD - 1) d1 = TP_HD - 1;
            uint4 vb0 = *(const uint4*)(Vtf + ((size_t)h * TP_HD + d0) * TP_LK + kk);
            uint4 vb1 = *(const uint4*)(Vtf + ((size_t)h * TP_HD + d1) * TP_LK + kk);
            __syncthreads();   // lsB reuse; first iter: lsP writes visible
            *(uint4*)(&lsB[r0 * 40 + c8])        = vb0;
            *(uint4*)(&lsB[(r0 + 64) * 40 + c8]) = vb1;
            __syncthreads();
            bf16x8 ap[4], bv[4];
#pragma unroll
            for (int mi = 0; mi < 4; ++mi)
                ap[mi] = *(const bf16x8*)(&lsP[pidx(wm + mi * 16 + c, kt * 32 + q * 8)]);
#pragma unroll
            for (int ni = 0; ni < 4; ++ni)
                bv[ni] = *(const bf16x8*)(&lsB[(wn + ni * 16 + c) * 40 + q * 8]);
#pragma unroll
            for (int mi = 0; mi < 4; ++mi)
#pragma unroll
                for (int ni = 0; ni < 4; ++ni)
                    acc_pv[mi][ni] = __builtin_amdgcn_mfma_f32_16x16x32_bf16(ap[mi], bv[ni], acc_pv[mi][ni], 0, 0, 0);
        }
    }

    // ---- ctx atomics (normal C/D layout: col=d, rows q*4+r)
#pragma unroll
    for (int mi = 0; mi < 4; ++mi) {
#pragma unroll
        for (int r = 0; r < 4; ++r) {
            const int qr = m0 + wm + mi * 16 + q * 4 + r;
            if (qr >= TP_LQ) continue;
#pragma unroll
            for (int ni = 0; ni < 4; ++ni) {
                const int d = wn + ni * 16 + c;
                if (d < TP_HD)
                    atomicAdd(&ctxF[(size_t)qr * TP_D + h * TP_HD + d], acc_pv[mi][ni][r]);
            }
        }
    }
}

// ---------------------------------------------------------------- frame finalize
// One thread per (h,query) row of FQ: l = sum_f F; lsum = l; block-reduce
// F/l into the 32 frame scores (pre-scaled by 1/196) via atomics into out.
__global__ __launch_bounds__(256) void frame_finalize(
        const float* __restrict__ FQ, float* __restrict__ lsum,
        float* __restrict__ frame_out) {
    __shared__ float red[256 * 33];
    const int tid = threadIdx.x;
    const int row = blockIdx.x * 256 + tid;   // 0..12543 exact (49*256)
    float v[32];
    const float4* src = (const float4*)(FQ + (size_t)row * TP_F);
    float l = 0.f;
#pragma unroll
    for (int i = 0; i < 8; ++i) {
        float4 t = src[i];
        v[4 * i + 0] = t.x; v[4 * i + 1] = t.y;
        v[4 * i + 2] = t.z; v[4 * i + 3] = t.w;
        l += (t.x + t.y) + (t.z + t.w);
    }
    lsum[row] = l;
    const float inv = 1.f / l;
#pragma unroll
    for (int f = 0; f < 32; ++f) red[tid * 33 + f] = v[f] * inv;
    __syncthreads();
    if (tid < 32) {
        float s = 0.f;
        for (int t = 0; t < 256; ++t) s += red[t * 33 + tid];
        atomicAdd(&frame_out[tid], s * (1.f / TP_P));
    }
}

// ---------------------------------------------------------------- layernorm
// t = x + bias + res; out = LN(t)*g + b
__global__ __launch_bounds__(256) void layernorm_rows(const float* __restrict__ x,
        const float* __restrict__ bias, const float* __restrict__ res,
        const float* __restrict__ g, const float* __restrict__ b,
        float* __restrict__ outF, u16* __restrict__ outB) {
    const int tid = threadIdx.x;
    const float* xr = x + (size_t)blockIdx.x * TP_D;
    const float* rr = res + (size_t)blockIdx.x * TP_D;
    float v[4];
#pragma unroll
    for (int i = 0; i < 4; ++i) {
        int idx = tid + i * 256;
        v[i] = (idx < TP_D) ? (xr[idx] + bias[idx] + rr[idx]) : 0.f;
    }
    float s = v[0] + v[1] + v[2] + v[3];
    __shared__ float red[4];
#pragma unroll
    for (int o = 32; o > 0; o >>= 1) s += __shfl_xor(s, o, 64);
    if ((tid & 63) == 0) red[tid >> 6] = s;
    __syncthreads();
    const float mu = (red[0] + red[1] + red[2] + red[3]) * (1.f / TP_D);
    __syncthreads();
    float ss = 0.f;
#pragma unroll
    for (int i = 0; i < 4; ++i) {
        int idx = tid + i * 256;
        if (idx < TP_D) { float d = v[i] - mu; ss += d * d; }
    }
#pragma unroll
    for (int o = 32; o > 0; o >>= 1) ss += __shfl_xor(ss, o, 64);
    if ((tid & 63) == 0) red[tid >> 6] = ss;
    __syncthreads();
    const float var = (red[0] + red[1] + red[2] + red[3]) * (1.f / TP_D);
    const float rsq = rsqrtf(var + 1e-12f);
    float* of = outF + (size_t)blockIdx.x * TP_D;
    u16* obp = outB ? outB + (size_t)blockIdx.x * TP_D : nullptr;
#pragma unroll
    for (int i = 0; i < 4; ++i) {
        int idx = tid + i * 256;
        if (idx < TP_D) {
            float y = (v[i] - mu) * rsq * g[idx] + b[idx];
            of[idx] = y;
            if (obp) obp[idx] = f2bf(y);
        }
    }
}

// ---------------------------------------------------------------- launch
extern "C" void kernel_launch(void* const* d_in, const int* in_sizes, int n_in,
                              void* d_out, int out_size, void* d_ws, size_t ws_size,
                              hipStream_t stream) {
    const float* img  = (const float*)d_in[0];
    const float* mem  = (const float*)d_in[1];
    const float* qW   = (const float*)d_in[2];
    const float* qb   = (const float*)d_in[3];
    const float* kW   = (const float*)d_in[4];
    const float* kb   = (const float*)d_in[5];
    const float* vW   = (const float*)d_in[6];
    const float* vb   = (const float*)d_in[7];
    const float* oW   = (const float*)d_in[8];
    const float* ob   = (const float*)d_in[9];
    const float* ln1g = (const float*)d_in[10];
    const float* ln1b = (const float*)d_in[11];
    const float* mW   = (const float*)d_in[12];
    const float* mb   = (const float*)d_in[13];
    const float* pW   = (const float*)d_in[14];
    const float* pb   = (const float*)d_in[15];
    const float* ln2g = (const float*)d_in[16];
    const float* ln2b = (const float*)d_in[17];
    float* out = (float*)d_out;

    char* base = (char*)d_ws;
    size_t off = 0;
    auto take = [&](size_t nbytes) -> void* {
        void* p = base + off;
        off += (nbytes + 255) & ~(size_t)255;
        return p;
    };

    u16* imgB  = (u16*)take((size_t)TP_LK * TP_D * 2);
    u16* memB  = (u16*)take((size_t)TP_LQ * TP_D * 2);
    u16* qWt   = (u16*)take((size_t)TP_D * TP_D * 2);
    u16* kWt   = (u16*)take((size_t)TP_D * TP_D * 2);
    u16* vWt   = (u16*)take((size_t)TP_D * TP_D * 2);
    u16* oWt   = (u16*)take((size_t)TP_D * TP_D * 2);
    u16* mWt   = (u16*)take((size_t)TP_D * TP_D4 * 2);
    u16* pWt   = (u16*)take((size_t)TP_D * TP_D4 * 2);
    u16* Qf    = (u16*)take((size_t)TP_LQ * TP_D * 2);
    u16* Kf    = (u16*)take((size_t)TP_LK * TP_D * 2);
    u16* Vtf   = (u16*)take((size_t)TP_LK * TP_D * 2);
    u16* ctxB  = (u16*)take((size_t)TP_LQ * TP_D * 2);
    float* attn  = (float*)take((size_t)TP_LQ * TP_D * 4);
    u16* attnB = (u16*)take((size_t)TP_LQ * TP_D * 2);
    u16* hidden= (u16*)take((size_t)TP_LQ * TP_D4 * 2);
    float* lsum  = (float*)take((size_t)TP_H * TP_LQ * 4);
    // ---- contiguous zero region (single memset) ----
    float* ctxF  = (float*)take((size_t)TP_LQ * TP_D * 4);
    float* pre1  = (float*)take((size_t)TP_LQ * TP_D * 4);
    float* pre2  = (float*)take((size_t)TP_LQ * TP_D * 4);
    float* FQ    = (float*)take((size_t)TP_H * TP_LQ * TP_F * 4);
    size_t zlen = (char*)(FQ + (size_t)TP_H * TP_LQ * TP_F) - (char*)ctxF;

    // ---- casts / transposes / zero-init
    {
        int n0 = TP_LK * TP_D, n1 = TP_LQ * TP_D;
        cast2_f32_bf16<<<((n0 + n1) / 4 + 255) / 256, 256, 0, stream>>>(img, imgB, n0, mem, memB, n1);
    }
    transpose_cast4<<<dim3(28, 28, 4), dim3(32, 8), 0, stream>>>(qW, qWt, kW, kWt, vW, vWt, oW, oWt);
    transpose_cast<<<dim3(TP_D4 / 32, TP_D / 32), dim3(32, 8), 0, stream>>>(mW, mWt, TP_D, TP_D4);
    transpose_cast<<<dim3(TP_D / 32, TP_D4 / 32), dim3(32, 8), 0, stream>>>(pW, pWt, TP_D4, TP_D);
    hipMemsetAsync(ctxF, 0, zlen, stream);
    hipMemsetAsync(out + (size_t)TP_LQ * TP_D, 0, TP_F * 4, stream);

    // ---- QKV projections in one dispatch (z: 0=K, 1=V^T, 2=Q)
    qkv_proj<<<dim3(14, 49, 3), 256, 0, stream>>>(imgB, memB, kWt, vWt, qWt,
                                                  kb, vb, qb, Kf, Vtf, Qf);

    // ---- fused attention (S + exp + FQ + PV), finalize (lsum + frame scores)
    const float scale = 0.09449111825230679f;  // 1/sqrt(112)
    attn_fused<<<dim3(7, 13, TP_H), 256, 0, stream>>>(Qf, Kf, Vtf, FQ, ctxF, scale);
    frame_finalize<<<49, 256, 0, stream>>>(FQ, lsum, out + (size_t)TP_LQ * TP_D);
    cast_div_bf16<<<(TP_LQ * TP_D / 4 + 255) / 256, 256, 0, stream>>>(ctxF, lsum, ctxB);

    // ---- O-projection split-K x2 -> pre1 (bias+residual in LN1)
    {
        GemmParams p{};
        p.A = ctxB; p.lda = TP_D;
        p.Bt = oWt; p.ldb = TP_D;
        p.M = TP_LQ; p.N = TP_D; p.K = 448; p.kc = 448;
        p.outF = pre1; p.ldc = TP_D;
        gemm_bf16<6><<<dim3(14, 13, 2), 256, 0, stream>>>(p);
    }
    layernorm_rows<<<TP_LQ, 256, 0, stream>>>(pre1, ob, mem, ln1g, ln1b, attn, attnB);

    // ---- MLP
    {
        GemmParams p{};
        p.A = attnB; p.lda = TP_D;
        p.Bt = mWt; p.ldb = TP_D;
        p.M = TP_LQ; p.N = TP_D4; p.K = TP_D;
        p.bias = mb; p.outB = hidden; p.ldc = TP_D4; p.relu = 1;
        gemm_bf16<4><<<dim3(56, 13, 1), 256, 0, stream>>>(p);
    }
    {   // MLP2 split-K x4 -> pre2 (bias+residual in LN2)
        GemmParams p{};
        p.A = hidden; p.lda = TP_D4;
        p.Bt = pWt; p.ldb = TP_D4;
        p.M = TP_LQ; p.N = TP_D; p.K = 896; p.kc = 896;
        p.outF = pre2; p.ldc = TP_D;
        gemm_bf16<6><<<dim3(14, 13, 4), 256, 0, stream>>>(p);
    }
    layernorm_rows<<<TP_LQ, 256, 0, stream>>>(pre2, pb, attn, ln2g, ln2b, out, nullptr);
}